// Round 1
// baseline (2300.265 us; speedup 1.0000x reference)
//
#include <hip/hip_runtime.h>
#include <hip/hip_bf16.h>
#include <math.h>

using bf16 = __hip_bfloat16;
#define DEV static __device__ __forceinline__

constexpr int BATCH = 8;
constexpr int CDIM  = 128;
constexpr int HIMG  = 128, WIMG = 128;
constexpr int NPIX  = HIMG * WIMG;          // 16384
constexpr int CPREV = 64, HPREV = 256, WPREV = 256;
constexpr int HNEXT = 64, WNEXT = 64;       // x_next spatial
constexpr int HEADS = 4;
constexpr int HIDF  = 340, CH2 = 680;

// ---- workspace arena (bytes). Overlays:
//   up_out (bf16, 8*512*4096) and h1 (bf16, 8*680*16384) live at OFF_QKVA
//   g (bf16, 8*340*16384) lives at OFF_F (f/y/attnout dead by then)
constexpr size_t SZ_MAIN_BF = (size_t)BATCH * CDIM * NPIX * 2;   // 32 MiB
constexpr size_t OFF_F    = 0;
constexpr size_t OFF_Y    = OFF_F    + SZ_MAIN_BF;
constexpr size_t OFF_ATTO = OFF_Y    + SZ_MAIN_BF;
constexpr size_t OFF_X    = OFF_ATTO + SZ_MAIN_BF;               // f32 x
constexpr size_t OFF_NORM = OFF_X    + (size_t)BATCH * CDIM * NPIX * 4;
constexpr size_t OFF_S    = OFF_NORM + (size_t)BATCH * 256 * 4;
constexpr size_t OFF_QKVA = OFF_S    + (size_t)BATCH * HEADS * 32 * 32 * 4;
constexpr size_t OFF_QKVB = OFF_QKVA + (size_t)BATCH * 384 * NPIX * 2;
constexpr size_t WS_NEED  = OFF_QKVB + (size_t)BATCH * 384 * NPIX * 2;  // ~352 MiB

DEV float bf2f(bf16 v) { return __bfloat162float(v); }
DEV bf16  f2bf(float v) { return __float2bfloat16(v); }
DEV float to_f(float v) { return v; }
DEV float to_f(bf16 v)  { return __bfloat162float(v); }

// ---------------------------------------------------------------------------
// Generic tiled GEMM: C[b][m][n] = sum_k A[m][k] * B[b][k][n]
// A: f32 weights [M][K]; B: TB (bf16 or f32), per-batch K x N channel-major.
// EPI 0: store bf16 to outB. EPI 1: outF = res + acc (f32, M must equal res's C).
// BM=BN=128, BK=16, 256 threads, 8x8 micro-tile.
// ---------------------------------------------------------------------------
template <typename TB, int EPI>
__global__ __launch_bounds__(256) void gemm_kernel(
    const float* __restrict__ A, const TB* __restrict__ B,
    const float* __restrict__ res, float* __restrict__ outF,
    bf16* __restrict__ outB, int M, int K, int N)
{
    __shared__ float As[16][128];
    __shared__ float Bs[16][128];
    const int t  = threadIdx.x;
    const int n0 = blockIdx.x * 128;
    const int m0 = blockIdx.y * 128;
    const int b  = blockIdx.z;
    const TB* Bp = B + (size_t)b * K * N;

    float acc[8][8];
#pragma unroll
    for (int i = 0; i < 8; i++)
#pragma unroll
        for (int j = 0; j < 8; j++) acc[i][j] = 0.f;

    const int tm = (t >> 4) << 3;
    const int tn = (t & 15) << 3;
    const int am = t >> 1, ak = (t & 1) << 3;
    const int bk = t >> 4, bn = (t & 15) << 3;

    for (int k0 = 0; k0 < K; k0 += 16) {
        // A tile (with M/K guards)
#pragma unroll
        for (int i = 0; i < 8; i++) {
            int kk = k0 + ak + i;
            As[ak + i][am] = (m0 + am < M && kk < K)
                               ? A[(size_t)(m0 + am) * K + kk] : 0.f;
        }
        // B tile
        {
            int kk = k0 + bk;
            if (kk < K) {
                const TB* src = Bp + (size_t)kk * N + n0 + bn;
#pragma unroll
                for (int i = 0; i < 8; i++) Bs[bk][bn + i] = to_f(src[i]);
            } else {
#pragma unroll
                for (int i = 0; i < 8; i++) Bs[bk][bn + i] = 0.f;
            }
        }
        __syncthreads();
#pragma unroll
        for (int kk = 0; kk < 16; kk++) {
            float a[8], bv[8];
#pragma unroll
            for (int i = 0; i < 8; i++) a[i]  = As[kk][tm + i];
#pragma unroll
            for (int j = 0; j < 8; j++) bv[j] = Bs[kk][tn + j];
#pragma unroll
            for (int i = 0; i < 8; i++)
#pragma unroll
                for (int j = 0; j < 8; j++)
                    acc[i][j] = fmaf(a[i], bv[j], acc[i][j]);
        }
        __syncthreads();
    }
#pragma unroll
    for (int i = 0; i < 8; i++) {
        int m = m0 + tm + i;
        if (m >= M) continue;
        size_t base = ((size_t)b * M + m) * N + n0 + tn;
        if (EPI == 0) {
#pragma unroll
            for (int j = 0; j < 8; j++) outB[base + j] = f2bf(acc[i][j]);
        } else {
#pragma unroll
            for (int j = 0; j < 8; j++) outF[base + j] = res[base + j] + acc[i][j];
        }
    }
}

// ---------------------------------------------------------------------------
// f = x_main + alpha_down * conv3x3s2(x_prev, down_w) + alpha_up * shuffle(up_out)
// block: 128 threads = output channel co; tile = 16 x-pixels at fixed (b,y).
// ---------------------------------------------------------------------------
__global__ __launch_bounds__(128) void fuse_down_kernel(
    const float* __restrict__ x_main, const float* __restrict__ x_prev,
    const float* __restrict__ down_w, const bf16* __restrict__ up_out,
    const float* __restrict__ alpha_down, const float* __restrict__ alpha_up,
    bf16* __restrict__ f)
{
    const int x0 = blockIdx.x * 16;
    const int y  = blockIdx.y;
    const int b  = blockIdx.z;
    const int co = threadIdx.x;

    __shared__ float sp[3][CPREV][36];  // [dy][ci][xc], rows 16B aligned
    const int total = 3 * CPREV * 33;
    for (int idx = threadIdx.x; idx < total; idx += 128) {
        int dy = idx / (CPREV * 33);
        int r  = idx % (CPREV * 33);
        int ci = r / 33, xc = r % 33;
        int iy = 2 * y - 1 + dy;
        int ix = 2 * x0 - 1 + xc;
        float v = 0.f;
        if (iy >= 0 && iy < HPREV && ix >= 0 && ix < WPREV)
            v = x_prev[(((size_t)b * CPREV + ci) * HPREV + iy) * WPREV + ix];
        sp[dy][ci][xc] = v;
    }
    __syncthreads();

    float acc[16];
#pragma unroll
    for (int px = 0; px < 16; px++) acc[px] = 0.f;

    const float* wbase = down_w + (size_t)co * (CPREV * 9);
    for (int ci = 0; ci < CPREV; ci++) {
        float w[9];
#pragma unroll
        for (int k = 0; k < 9; k++) w[k] = wbase[ci * 9 + k];
#pragma unroll
        for (int dy = 0; dy < 3; dy++) {
            float r[33];
#pragma unroll
            for (int q = 0; q < 33; q++) r[q] = sp[dy][ci][q];
#pragma unroll
            for (int px = 0; px < 16; px++) {
                acc[px] = fmaf(w[dy*3+0], r[2*px],
                          fmaf(w[dy*3+1], r[2*px+1],
                          fmaf(w[dy*3+2], r[2*px+2], acc[px])));
            }
        }
    }

    const float ad = alpha_down[0], au = alpha_up[0];
    const int ys = y >> 1, r1 = y & 1;
#pragma unroll
    for (int px = 0; px < 16; px++) {
        int x = x0 + px;
        int cp = (co << 2) | (r1 << 1) | (x & 1);
        float up = bf2f(up_out[(((size_t)b * 512 + cp) * HNEXT + ys) * WNEXT + (x >> 1)]);
        size_t mi = ((size_t)b * CDIM + co) * NPIX + (size_t)y * WIMG + x;
        f[mi] = f2bf(x_main[mi] + ad * acc[px] + au * up);
    }
}

// ---------------------------------------------------------------------------
// Channel LayerNorm (over C=128), eps 1e-5, affine. One thread per pixel.
// ---------------------------------------------------------------------------
template <typename TI>
__global__ __launch_bounds__(256) void ln_kernel(
    const TI* __restrict__ in, const float* __restrict__ w,
    const float* __restrict__ bias, bf16* __restrict__ out)
{
    int p = blockIdx.x * 256 + threadIdx.x;
    size_t base = (size_t)(p / NPIX) * CDIM * NPIX + (p % NPIX);
    float s = 0.f, ss = 0.f;
    for (int c = 0; c < CDIM; c++) {
        float v = to_f(in[base + (size_t)c * NPIX]);
        s += v; ss += v * v;
    }
    float mean = s * (1.f / 128.f);
    float var  = ss * (1.f / 128.f) - mean * mean;
    float rstd = rsqrtf(var + 1e-5f);
    for (int c = 0; c < CDIM; c++) {
        float v = to_f(in[base + (size_t)c * NPIX]);
        out[base + (size_t)c * NPIX] = f2bf((v - mean) * rstd * w[c] + bias[c]);
    }
}

// ---------------------------------------------------------------------------
// Depthwise 3x3 pad=1 (plain), bf16 in/out, f32 weights [Ctot][9].
// ---------------------------------------------------------------------------
__global__ __launch_bounds__(256) void dwconv_kernel(
    const bf16* __restrict__ in, const float* __restrict__ w,
    bf16* __restrict__ out, int Ctot)
{
    size_t idx = (size_t)blockIdx.x * 256 + threadIdx.x;
    int n = (int)(idx % NPIX);
    int c = (int)((idx / NPIX) % Ctot);
    int y = n >> 7, x = n & 127;
    const bf16* base = in + (idx - n);
    const float* wr = w + (size_t)c * 9;
    float acc = 0.f;
#pragma unroll
    for (int dy = -1; dy <= 1; dy++) {
        int yy = y + dy; if (yy < 0 || yy >= HIMG) continue;
#pragma unroll
        for (int dx = -1; dx <= 1; dx++) {
            int xx = x + dx; if (xx < 0 || xx >= WIMG) continue;
            acc = fmaf(wr[(dy+1)*3 + (dx+1)], bf2f(base[yy * WIMG + xx]), acc);
        }
    }
    out[idx] = f2bf(acc);
}

// ---------------------------------------------------------------------------
// 1/max(||row||2, 1e-12) for q rows (ch 0..127) and k rows (ch 128..255).
// block per (b, c): 8*256 blocks.
// ---------------------------------------------------------------------------
__global__ __launch_bounds__(256) void rownorm_kernel(
    const bf16* __restrict__ qkv, float* __restrict__ inv)
{
    int b = blockIdx.x >> 8, c = blockIdx.x & 255;
    const bf16* row = qkv + ((size_t)b * 384 + c) * NPIX;
    float ss = 0.f;
    for (int i = threadIdx.x; i < NPIX; i += 256) {
        float v = bf2f(row[i]); ss = fmaf(v, v, ss);
    }
#pragma unroll
    for (int off = 32; off >= 1; off >>= 1) ss += __shfl_down(ss, off);
    __shared__ float red[4];
    if ((threadIdx.x & 63) == 0) red[threadIdx.x >> 6] = ss;
    __syncthreads();
    if (threadIdx.x == 0) {
        float t = red[0] + red[1] + red[2] + red[3];
        inv[blockIdx.x] = 1.f / fmaxf(sqrtf(t), 1e-12f);
    }
}

// ---------------------------------------------------------------------------
// Channel-attention scores: S[b,h,i,j] += sum over an n-chunk of q_i * k_j.
// grid (32 bh, 32 chunks), 256 threads; atomic f32 accumulate (S memset first).
// ---------------------------------------------------------------------------
constexpr int NCHUNK = 512;
__global__ __launch_bounds__(256) void scores_kernel(
    const bf16* __restrict__ qkv, float* __restrict__ S)
{
    int bh = blockIdx.x, b = bh >> 2, h = bh & 3;
    int nb = blockIdx.y;
    __shared__ bf16 sq[32][NCHUNK];
    __shared__ bf16 sk[32][NCHUNK];
    const bf16* qbase = qkv + ((size_t)b * 384 + h * 32) * NPIX + (size_t)nb * NCHUNK;
    const bf16* kbase = qkv + ((size_t)b * 384 + 128 + h * 32) * NPIX + (size_t)nb * NCHUNK;
    for (int idx = threadIdx.x; idx < 32 * NCHUNK; idx += 256) {
        int d = idx >> 9, n = idx & (NCHUNK - 1);
        sq[d][n] = qbase[(size_t)d * NPIX + n];
        sk[d][n] = kbase[(size_t)d * NPIX + n];
    }
    __syncthreads();
    int i = threadIdx.x >> 3, jb = threadIdx.x & 7;
    float a0 = 0.f, a1 = 0.f, a2 = 0.f, a3 = 0.f;
    for (int n = 0; n < NCHUNK; n++) {
        float qv = bf2f(sq[i][n]);
        a0 = fmaf(qv, bf2f(sk[jb     ][n]), a0);
        a1 = fmaf(qv, bf2f(sk[jb +  8][n]), a1);
        a2 = fmaf(qv, bf2f(sk[jb + 16][n]), a2);
        a3 = fmaf(qv, bf2f(sk[jb + 24][n]), a3);
    }
    float* Srow = S + (size_t)bh * 1024 + (size_t)i * 32 + jb;
    atomicAdd(&Srow[0],  a0);
    atomicAdd(&Srow[8],  a1);
    atomicAdd(&Srow[16], a2);
    atomicAdd(&Srow[24], a3);
}

// softmax over j with temperature and q/k norm scaling; in-place on S.
__global__ void softmax_kernel(float* __restrict__ S, const float* __restrict__ inv,
                               const float* __restrict__ temp)
{
    int bh = blockIdx.x, b = bh >> 2, h = bh & 3;
    int i = threadIdx.x;            // 32 threads, one row each
    float* row = S + (size_t)bh * 1024 + (size_t)i * 32;
    float ti = temp[h] * inv[b * 256 + h * 32 + i];
    float vals[32];
    float m = -1e30f;
#pragma unroll
    for (int j = 0; j < 32; j++) {
        float v = row[j] * ti * inv[b * 256 + 128 + h * 32 + j];
        vals[j] = v; m = fmaxf(m, v);
    }
    float s = 0.f;
#pragma unroll
    for (int j = 0; j < 32; j++) { vals[j] = expf(vals[j] - m); s += vals[j]; }
    float r = 1.f / s;
#pragma unroll
    for (int j = 0; j < 32; j++) row[j] = vals[j] * r;
}

// out[b, h*32+c, n] = sum_d attn[c,d] * v[d,n]; tile 32c x 128n per block.
__global__ __launch_bounds__(256) void attnapply_kernel(
    const bf16* __restrict__ qkv, const float* __restrict__ S,
    bf16* __restrict__ out)
{
    int bh = blockIdx.x, b = bh >> 2, h = bh & 3;
    int n0 = blockIdx.y * 128;
    __shared__ float sa[32][32];
    __shared__ bf16  sv[32][128];
    for (int idx = threadIdx.x; idx < 1024; idx += 256)
        sa[idx >> 5][idx & 31] = S[(size_t)bh * 1024 + idx];
    const bf16* vbase = qkv + ((size_t)b * 384 + 256 + h * 32) * NPIX + n0;
    for (int idx = threadIdx.x; idx < 32 * 128; idx += 256) {
        int d = idx >> 7, nn = idx & 127;
        sv[d][nn] = vbase[(size_t)d * NPIX + nn];
    }
    __syncthreads();
    int nn = threadIdx.x & 127, half = threadIdx.x >> 7;
    float vv[32];
#pragma unroll
    for (int d = 0; d < 32; d++) vv[d] = bf2f(sv[d][nn]);
    bf16* obase = out + ((size_t)b * CDIM + h * 32) * NPIX + n0 + nn;
#pragma unroll
    for (int ci = 0; ci < 16; ci++) {
        int c = half * 16 + ci;
        float acc = 0.f;
#pragma unroll
        for (int d = 0; d < 32; d++) acc = fmaf(sa[c][d], vv[d], acc);
        obase[(size_t)c * NPIX] = f2bf(acc);
    }
}

// Fused FFN depthwise 3x3 + exact GELU gate: g[c] = gelu(dw(c)) * dw(c+340).
__global__ __launch_bounds__(256) void dwgate_kernel(
    const bf16* __restrict__ h1, const float* __restrict__ w,
    bf16* __restrict__ g)
{
    size_t idx = (size_t)blockIdx.x * 256 + threadIdx.x;
    int n = (int)(idx % NPIX);
    int c = (int)((idx / NPIX) % HIDF);
    int b = (int)(idx / ((size_t)NPIX * HIDF));
    int y = n >> 7, x = n & 127;
    const bf16* b1 = h1 + ((size_t)b * CH2 + c) * NPIX;
    const bf16* b2 = h1 + ((size_t)b * CH2 + c + HIDF) * NPIX;
    const float* w1 = w + (size_t)c * 9;
    const float* w2 = w + (size_t)(c + HIDF) * 9;
    float a1 = 0.f, a2 = 0.f;
#pragma unroll
    for (int dy = -1; dy <= 1; dy++) {
        int yy = y + dy; if (yy < 0 || yy >= HIMG) continue;
#pragma unroll
        for (int dx = -1; dx <= 1; dx++) {
            int xx = x + dx; if (xx < 0 || xx >= WIMG) continue;
            int k = (dy + 1) * 3 + (dx + 1);
            int off = yy * WIMG + xx;
            a1 = fmaf(w1[k], bf2f(b1[off]), a1);
            a2 = fmaf(w2[k], bf2f(b2[off]), a2);
        }
    }
    float ge = 0.5f * a1 * (1.f + erff(a1 * 0.7071067811865476f));
    g[idx] = f2bf(ge * a2);
}

// ---------------------------------------------------------------------------
extern "C" void kernel_launch(void* const* d_in, const int* in_sizes, int n_in,
                              void* d_out, int out_size, void* d_ws, size_t ws_size,
                              hipStream_t stream)
{
    const float* x_main      = (const float*)d_in[0];
    const float* x_prev      = (const float*)d_in[1];
    const float* x_next      = (const float*)d_in[2];
    const float* alpha_down  = (const float*)d_in[3];
    const float* alpha_up    = (const float*)d_in[4];
    const float* down_w      = (const float*)d_in[5];
    const float* up_w        = (const float*)d_in[6];
    const float* norm1_w     = (const float*)d_in[7];
    const float* norm1_b     = (const float*)d_in[8];
    const float* temperature = (const float*)d_in[9];
    const float* qkv_w       = (const float*)d_in[10];
    const float* qkv_dw_w    = (const float*)d_in[11];
    const float* proj_w      = (const float*)d_in[12];
    const float* norm2_w     = (const float*)d_in[13];
    const float* norm2_b     = (const float*)d_in[14];
    const float* ffn_in_w    = (const float*)d_in[15];
    const float* ffn_dw_w    = (const float*)d_in[16];
    const float* ffn_out_w   = (const float*)d_in[17];
    float* out = (float*)d_out;

    char* ws = (char*)d_ws;
    bf16*  f_buf   = (bf16*)(ws + OFF_F);
    bf16*  y_buf   = (bf16*)(ws + OFF_Y);       // y1 then y2
    bf16*  atto    = (bf16*)(ws + OFF_ATTO);
    float* x_buf   = (float*)(ws + OFF_X);
    float* normbuf = (float*)(ws + OFF_NORM);
    float* S_buf   = (float*)(ws + OFF_S);
    bf16*  qkv_a   = (bf16*)(ws + OFF_QKVA);
    bf16*  qkv_b   = (bf16*)(ws + OFF_QKVB);
    bf16*  up_out  = (bf16*)(ws + OFF_QKVA);    // alias (dead before qkv_a written)
    bf16*  h1_buf  = (bf16*)(ws + OFF_QKVA);    // alias, spans qkv_a+qkv_b
    bf16*  g_buf   = (bf16*)(ws + OFF_F);       // alias, spans f+y+attnout

    (void)in_sizes; (void)n_in; (void)out_size; (void)ws_size;

    // 1) up-path 1x1 conv as GEMM: up_out[b,512,4096] = up_w @ x_next
    gemm_kernel<float, 0><<<dim3(WNEXT * HNEXT / 128, 512 / 128, BATCH), 256, 0, stream>>>(
        up_w, x_next, nullptr, nullptr, up_out, 512, 256, WNEXT * HNEXT);

    // 2) f = x_main + ad*down(x_prev) + au*pixel_shuffle(up_out)
    fuse_down_kernel<<<dim3(WIMG / 16, HIMG, BATCH), 128, 0, stream>>>(
        x_main, x_prev, down_w, up_out, alpha_down, alpha_up, f_buf);

    // 3) y1 = LN(f)
    ln_kernel<bf16><<<BATCH * NPIX / 256, 256, 0, stream>>>(f_buf, norm1_w, norm1_b, y_buf);

    // 4) qkv_a = qkv_w @ y1
    gemm_kernel<bf16, 0><<<dim3(NPIX / 128, 3, BATCH), 256, 0, stream>>>(
        qkv_w, y_buf, nullptr, nullptr, qkv_a, 384, 128, NPIX);

    // 5) qkv_b = depthwise3x3(qkv_a)
    dwconv_kernel<<<(int)(((size_t)BATCH * 384 * NPIX) / 256), 256, 0, stream>>>(
        qkv_a, qkv_dw_w, qkv_b, 384);

    // 6) q/k row inverse norms
    rownorm_kernel<<<BATCH * 256, 256, 0, stream>>>(qkv_b, normbuf);

    // 7) scores (atomic partial sums) + softmax
    hipMemsetAsync(S_buf, 0, (size_t)BATCH * HEADS * 32 * 32 * 4, stream);
    scores_kernel<<<dim3(BATCH * HEADS, NPIX / NCHUNK), 256, 0, stream>>>(qkv_b, S_buf);
    softmax_kernel<<<BATCH * HEADS, 32, 0, stream>>>(S_buf, normbuf, temperature);

    // 8) attnout = attn @ v
    attnapply_kernel<<<dim3(BATCH * HEADS, NPIX / 128), 256, 0, stream>>>(qkv_b, S_buf, atto);

    // 9) x = x_main + proj_w @ attnout
    gemm_kernel<bf16, 1><<<dim3(NPIX / 128, 1, BATCH), 256, 0, stream>>>(
        proj_w, atto, x_main, x_buf, nullptr, 128, 128, NPIX);

    // 10) y2 = LN(x)
    ln_kernel<float><<<BATCH * NPIX / 256, 256, 0, stream>>>(x_buf, norm2_w, norm2_b, y_buf);

    // 11) h1 = ffn_in_w @ y2  (680 channels)
    gemm_kernel<bf16, 0><<<dim3(NPIX / 128, (CH2 + 127) / 128, BATCH), 256, 0, stream>>>(
        ffn_in_w, y_buf, nullptr, nullptr, h1_buf, CH2, 128, NPIX);

    // 12) g = gelu(dw(h1[:340])) * dw(h1[340:])
    dwgate_kernel<<<(int)(((size_t)BATCH * HIDF * NPIX) / 256), 256, 0, stream>>>(
        h1_buf, ffn_dw_w, g_buf);

    // 13) out = x + ffn_out_w @ g
    gemm_kernel<bf16, 1><<<dim3(NPIX / 128, 1, BATCH), 256, 0, stream>>>(
        ffn_out_w, g_buf, x_buf, out, nullptr, 128, HIDF, NPIX);
}

// Round 2
// 970.277 us; speedup vs baseline: 2.3707x; 2.3707x over previous
//
#include <hip/hip_runtime.h>
#include <hip/hip_bf16.h>
#include <math.h>

using bf16 = __hip_bfloat16;
#define DEV static __device__ __forceinline__

typedef float  fx4   __attribute__((ext_vector_type(4)));
typedef short  s16x8 __attribute__((ext_vector_type(8)));
typedef short  s16x4 __attribute__((ext_vector_type(4)));
typedef __bf16 bfx8  __attribute__((ext_vector_type(8)));

constexpr int BATCH = 8;
constexpr int CDIM  = 128;
constexpr int NPIX  = 16384;      // 128x128
constexpr int HIDF  = 340;
constexpr int KFF   = 352;        // padded K for ffn_out
constexpr int MFI   = 768;        // padded M for ffn_in (true 680)

DEV float uu2f(unsigned short u) { return __uint_as_float(((unsigned)u) << 16); }
DEV unsigned short f2us(float f) { bf16 h = __float2bfloat16(f); return *(unsigned short*)&h; }
DEV float bl2f(bf16 v) { return __bfloat162float(v); }

// ---------------- workspace layout (bytes) ----------------
constexpr size_t OFF_SL1   = 0;                    // 178.3MB: {xnext_pm,up_pm,xprev_pm} -> qkv_a -> h1
constexpr size_t OFF_XNEXT = OFF_SL1;              // 16.78MB
constexpr size_t OFF_UP    = OFF_SL1 + 16777216;   // 33.55MB
constexpr size_t OFF_XPREV = OFF_SL1 + 50331648;   // 67.1MB
constexpr size_t SZ_SL1    = 178257920;            // h1 = 8*16384*680*2
constexpr size_t OFF_SL2   = OFF_SL1 + SZ_SL1;     // 100.7MB: qkv_b -> g
constexpr size_t OFF_SL3   = OFF_SL2 + 100663296;  // 33.55MB: y1 -> atto
constexpr size_t OFF_SL4   = OFF_SL3 + 33554432;   // 33.55MB: x (bf16 pm)
constexpr size_t OFF_SL5   = OFF_SL4 + 33554432;   // 33.55MB: y2
constexpr size_t OFF_W     = OFF_SL5 + 33554432;
constexpr size_t OFF_WUP   = OFF_W;                // 512*256*2
constexpr size_t OFF_WQKV  = OFF_W +  262144;      // 384*128*2
constexpr size_t OFF_WPRJ  = OFF_W +  360448;      // 128*128*2
constexpr size_t OFF_WFIN  = OFF_W +  393216;      // 768*128*2
constexpr size_t OFF_WFOUT = OFF_W +  589824;      // 128*352*2
constexpr size_t OFF_WDWN  = OFF_W +  679936;      // 64*9*128*4 f32
constexpr size_t OFF_NBUF  = OFF_W +  974848;      // 8*256*4
constexpr size_t OFF_S     = OFF_W +  983040;      // 32*1024*4

// ---------------------------------------------------------------------------
// generic f32 -> bf16 weight convert with zero padding
// ---------------------------------------------------------------------------
__global__ void conv_pad(const float* __restrict__ src, bf16* __restrict__ dst,
                         int Rs, int Cs, int Rd, int Cd)
{
    int n = Rd * Cd;
    for (int i = blockIdx.x * 256 + threadIdx.x; i < n; i += gridDim.x * 256) {
        int r = i / Cd, c = i % Cd;
        dst[i] = (r < Rs && c < Cs) ? __float2bfloat16(src[r * Cs + c]) : bf16(0.f);
    }
}

// down_w [128co][64ci][9] f32  ->  [64ci][9k][128co] f32
__global__ void wdwn_perm(const float* __restrict__ src, float* __restrict__ dst)
{
    int i = blockIdx.x * 256 + threadIdx.x;
    if (i >= 64 * 9 * 128) return;
    int ci = i / 1152, rm = i % 1152, k = rm / 128, co = rm % 128;
    dst[i] = src[((size_t)co * 64 + ci) * 9 + k];
}

// NCHW f32 -> pixel-major bf16 transpose
__global__ __launch_bounds__(256) void transpose_c2p(
    const float* __restrict__ in, bf16* __restrict__ out, int C, int HW)
{
    __shared__ float ts[32][33];
    int hw0 = blockIdx.x * 32, c0 = blockIdx.y * 32, b = blockIdx.z;
    int rl = threadIdx.x >> 5, cl = threadIdx.x & 31;
#pragma unroll
    for (int i = 0; i < 4; i++)
        ts[rl + i * 8][cl] = in[((size_t)b * C + c0 + rl + i * 8) * HW + hw0 + cl];
    __syncthreads();
#pragma unroll
    for (int i = 0; i < 4; i++)
        out[((size_t)b * HW + hw0 + rl + i * 8) * C + c0 + cl] =
            __float2bfloat16(ts[cl][rl + i * 8]);
}

// ---------------------------------------------------------------------------
// MFMA GEMM: D[b][n][co] = sum_k Act[b][n][k] * Wt[co][k]
// tile 128n x 128co, BK=32, 4 waves (2x2), 16x16x32 bf16 MFMA.
// EPI 0: store bf16 pm (guard co<Mtrue, stride Mstride)
// EPI 1: x = x_main^T + D; fused LN over 128 co -> y2 (outB) + x bf16 (x_out)
// EPI 2: out_nchw = xres_pm + D (f32 NCHW store)
// ---------------------------------------------------------------------------
template <int EPI>
__global__ __launch_bounds__(256) void gemm_mfma(
    const bf16* __restrict__ Act, const bf16* __restrict__ Wt,
    int K, int Npb, int Mtrue, int Mstride,
    bf16* __restrict__ outB,
    const float* __restrict__ xmain, bf16* __restrict__ x_out,
    const float* __restrict__ nw, const float* __restrict__ nb,
    const bf16* __restrict__ xres, float* __restrict__ outF)
{
    __shared__ short As[128 * 32];
    __shared__ short Bs[128 * 32];
    const int t = threadIdx.x;
    const int w = t >> 6, lane = t & 63;
    const int wr = w >> 1, wc = w & 1;
    const int lr = lane & 15, lg = lane >> 4;
    const int n0 = blockIdx.x * 128;
    const int m0 = blockIdx.y * 128;
    const int b  = blockIdx.z;
    const bf16* Abase = Act + (size_t)b * Npb * K;

    fx4 acc[4][4];
#pragma unroll
    for (int i = 0; i < 4; i++)
#pragma unroll
        for (int j = 0; j < 4; j++) acc[i][j] = fx4{0.f, 0.f, 0.f, 0.f};

    const int f0 = w * 128 + lane, f1 = f0 + 64;
    const int r0 = f0 >> 2, c0 = (f0 & 3) * 8;
    const int r1 = f1 >> 2, c1 = (f1 & 3) * 8;

    for (int ks = 0; ks < K; ks += 32) {
        __builtin_amdgcn_global_load_lds(
            (const __attribute__((address_space(1))) void*)(Abase + (size_t)(n0 + r0) * K + ks + c0),
            (__attribute__((address_space(3))) void*)(As + w * 1024), 16, 0, 0);
        __builtin_amdgcn_global_load_lds(
            (const __attribute__((address_space(1))) void*)(Abase + (size_t)(n0 + r1) * K + ks + c1),
            (__attribute__((address_space(3))) void*)(As + w * 1024 + 512), 16, 0, 0);
        __builtin_amdgcn_global_load_lds(
            (const __attribute__((address_space(1))) void*)(Wt + (size_t)(m0 + r0) * K + ks + c0),
            (__attribute__((address_space(3))) void*)(Bs + w * 1024), 16, 0, 0);
        __builtin_amdgcn_global_load_lds(
            (const __attribute__((address_space(1))) void*)(Wt + (size_t)(m0 + r1) * K + ks + c1),
            (__attribute__((address_space(3))) void*)(Bs + w * 1024 + 512), 16, 0, 0);
        __syncthreads();
        bfx8 af[4], bw[4];
#pragma unroll
        for (int mi = 0; mi < 4; mi++)
            af[mi] = __builtin_bit_cast(bfx8,
                *(const s16x8*)&As[(wr * 64 + mi * 16 + lr) * 32 + lg * 8]);
#pragma unroll
        for (int ni = 0; ni < 4; ni++)
            bw[ni] = __builtin_bit_cast(bfx8,
                *(const s16x8*)&Bs[(wc * 64 + ni * 16 + lr) * 32 + lg * 8]);
#pragma unroll
        for (int mi = 0; mi < 4; mi++)
#pragma unroll
            for (int ni = 0; ni < 4; ni++)
                acc[mi][ni] = __builtin_amdgcn_mfma_f32_16x16x32_bf16(
                    af[mi], bw[ni], acc[mi][ni], 0, 0, 0);
        __syncthreads();
    }

    if (EPI == 0) {
#pragma unroll
        for (int mi = 0; mi < 4; mi++)
#pragma unroll
            for (int ni = 0; ni < 4; ni++) {
                int co = m0 + wc * 64 + ni * 16 + lr;
                if (co < Mtrue) {
#pragma unroll
                    for (int r = 0; r < 4; r++) {
                        int px = n0 + wr * 64 + mi * 16 + lg * 4 + r;
                        outB[((size_t)b * Npb + px) * Mstride + co] =
                            __float2bfloat16(acc[mi][ni][r]);
                    }
                }
            }
    } else if (EPI == 1) {
        float xv[4][4][4];
#pragma unroll
        for (int mi = 0; mi < 4; mi++)
#pragma unroll
            for (int ni = 0; ni < 4; ni++) {
                int co = wc * 64 + ni * 16 + lr;
                fx4 x4 = *(const fx4*)&xmain[((size_t)b * 128 + co) * 16384 +
                                             n0 + wr * 64 + mi * 16 + lg * 4];
#pragma unroll
                for (int r = 0; r < 4; r++) xv[mi][ni][r] = x4[r] + acc[mi][ni][r];
            }
        __shared__ float ps[2][128];
        __shared__ float pss[2][128];
#pragma unroll
        for (int mi = 0; mi < 4; mi++)
#pragma unroll
            for (int r = 0; r < 4; r++) {
                float s = 0.f, s2 = 0.f;
#pragma unroll
                for (int ni = 0; ni < 4; ni++) {
                    float v = xv[mi][ni][r]; s += v; s2 += v * v;
                }
#pragma unroll
                for (int m = 1; m < 16; m <<= 1) {
                    s  += __shfl_xor(s, m);
                    s2 += __shfl_xor(s2, m);
                }
                if (lr == 0) {
                    int row = wr * 64 + mi * 16 + lg * 4 + r;
                    ps[wc][row] = s; pss[wc][row] = s2;
                }
            }
        __syncthreads();
        float nwv[4], nbv[4];
#pragma unroll
        for (int ni = 0; ni < 4; ni++) {
            int co = wc * 64 + ni * 16 + lr;
            nwv[ni] = nw[co]; nbv[ni] = nb[co];
        }
#pragma unroll
        for (int mi = 0; mi < 4; mi++)
#pragma unroll
            for (int r = 0; r < 4; r++) {
                int row = wr * 64 + mi * 16 + lg * 4 + r;
                float s  = ps[0][row] + ps[1][row];
                float s2 = pss[0][row] + pss[1][row];
                float mu = s * (1.f / 128.f);
                float var = s2 * (1.f / 128.f) - mu * mu;
                float rstd = rsqrtf(var + 1e-5f);
                size_t px = (size_t)b * 16384 + n0 + row;
#pragma unroll
                for (int ni = 0; ni < 4; ni++) {
                    int co = wc * 64 + ni * 16 + lr;
                    float v = xv[mi][ni][r];
                    x_out[px * 128 + co] = __float2bfloat16(v);
                    outB[px * 128 + co] = __float2bfloat16((v - mu) * rstd * nwv[ni] + nbv[ni]);
                }
            }
    } else {  // EPI 2
#pragma unroll
        for (int mi = 0; mi < 4; mi++)
#pragma unroll
            for (int ni = 0; ni < 4; ni++) {
                int co = wc * 64 + ni * 16 + lr;
                int pxb = n0 + wr * 64 + mi * 16 + lg * 4;
                fx4 o;
#pragma unroll
                for (int r = 0; r < 4; r++)
                    o[r] = acc[mi][ni][r] +
                           bl2f(xres[((size_t)b * 16384 + pxb + r) * 128 + co]);
                *(fx4*)&outF[((size_t)b * 128 + co) * 16384 + pxb] = o;
            }
    }
}

// ---------------------------------------------------------------------------
// fuse_down + LN1: y1 = LN(x_main + ad*conv3x3s2(x_prev) + au*shuffle(up)) (pm)
// block: 32 out px (fixed y) x 128 co; thread: 4 px x 4 co.
// ---------------------------------------------------------------------------
__global__ __launch_bounds__(256) void fuse_down_ln(
    const bf16* __restrict__ xprev_pm,   // [b][65536][64]
    const float* __restrict__ xmain,     // NCHW f32
    const bf16* __restrict__ up_pm,      // [b][4096][512]
    const float* __restrict__ wdwn,      // [64ci][9][128co] f32
    const float* __restrict__ alpha_d, const float* __restrict__ alpha_u,
    const float* __restrict__ n1w, const float* __restrict__ n1b,
    bf16* __restrict__ y1)               // [b][16384][128]
{
    __shared__ short patch[3 * 64 * 72];   // [dy][ci][72 ix]  (65 used)
    __shared__ float wsm[8 * 9 * 128];     // [ci8][9][128co]
    const int t = threadIdx.x;
    const int p = t >> 5, q = t & 31;
    const int x0 = blockIdx.x * 32;
    const int y  = blockIdx.y;
    const int b  = blockIdx.z;
    const int ix0 = 2 * x0 - 1;

    // zero patch
    for (int i = t; i < 3456; i += 256) ((s16x8*)patch)[i] = s16x8{0,0,0,0,0,0,0,0};
    __syncthreads();
    // stage patch (transposing: src ci-contig -> dst ix-contig)
    for (int g = t; g < 1560; g += 256) {
        int dy = g / 520, rm = g % 520, ixl = rm >> 3, c8 = rm & 7;
        int iy = 2 * y - 1 + dy;
        int ix = ix0 + ixl;
        if (iy >= 0 && ix >= 0 && ix < 256) {
            s16x8 v = *(const s16x8*)((const short*)xprev_pm +
                        ((size_t)b * 65536 + iy * 256 + ix) * 64 + c8 * 8);
#pragma unroll
            for (int cc = 0; cc < 8; cc++)
                patch[(dy * 64 + c8 * 8 + cc) * 72 + ixl] = v[cc];
        }
    }

    fx4 acc[4];
#pragma unroll
    for (int j = 0; j < 4; j++) acc[j] = fx4{0.f, 0.f, 0.f, 0.f};

    for (int chunk = 0; chunk < 8; chunk++) {
        __syncthreads();
        for (int i = t; i < 2304; i += 256)
            ((fx4*)wsm)[i] = ((const fx4*)(wdwn + chunk * 9216))[i];
        __syncthreads();
#pragma unroll
        for (int cil = 0; cil < 8; cil++) {
            int ci = chunk * 8 + cil;
            fx4 wv[9];
#pragma unroll
            for (int k = 0; k < 9; k++)
                wv[k] = *(const fx4*)&wsm[(cil * 9 + k) * 128 + q * 4];
#pragma unroll
            for (int dy = 0; dy < 3; dy++) {
                const short* base = &patch[(dy * 64 + ci) * 72 + 8 * p];
                s16x8 r8 = *(const s16x8*)base;
                unsigned r2 = *(const unsigned*)(base + 8);
                float rv[10];
#pragma unroll
                for (int e = 0; e < 8; e++) rv[e] = uu2f((unsigned short)r8[e]);
                rv[8] = uu2f((unsigned short)(r2 & 0xffff));
                rv[9] = uu2f((unsigned short)(r2 >> 16));
#pragma unroll
                for (int dx = 0; dx < 3; dx++) {
                    fx4 wk = wv[dy * 3 + dx];
#pragma unroll
                    for (int j = 0; j < 4; j++)
                        acc[j] += wk * rv[2 * j + dx];
                }
            }
        }
    }

    const float ad = alpha_d[0], au = alpha_u[0];
    const int xbase = x0 + p * 4;
    fx4 xm[4];
#pragma unroll
    for (int cc = 0; cc < 4; cc++) {
        int co = q * 4 + cc;
        xm[cc] = *(const fx4*)&xmain[(((size_t)b * 128 + co) << 14) + (y << 7) + xbase];
    }
    fx4 fv[4];
#pragma unroll
    for (int j = 0; j < 4; j++) {
        int x = xbase + j;
        int n2 = ((y >> 1) << 6) + (x >> 1);
        int chb = ((y & 1) << 1) + (x & 1);
#pragma unroll
        for (int cc = 0; cc < 4; cc++) {
            int co = q * 4 + cc;
            float up = bl2f(up_pm[((size_t)b * 4096 + n2) * 512 + co * 4 + chb]);
            fv[j][cc] = xm[cc][j] + ad * acc[j][cc] + au * up;
        }
    }
    fx4 w1 = *(const fx4*)&n1w[q * 4];
    fx4 b1 = *(const fx4*)&n1b[q * 4];
#pragma unroll
    for (int j = 0; j < 4; j++) {
        float s = fv[j][0] + fv[j][1] + fv[j][2] + fv[j][3];
        float s2 = fv[j][0]*fv[j][0] + fv[j][1]*fv[j][1] + fv[j][2]*fv[j][2] + fv[j][3]*fv[j][3];
#pragma unroll
        for (int m = 1; m < 32; m <<= 1) {
            s  += __shfl_xor(s, m);
            s2 += __shfl_xor(s2, m);
        }
        float mu = s * (1.f / 128.f);
        float var = s2 * (1.f / 128.f) - mu * mu;
        float rstd = rsqrtf(var + 1e-5f);
        s16x4 pk;
#pragma unroll
        for (int cc = 0; cc < 4; cc++)
            pk[cc] = (short)f2us((fv[j][cc] - mu) * rstd * w1[cc] + b1[cc]);
        *(s16x4*)((short*)y1 + ((size_t)b * 16384 + (y << 7) + xbase + j) * 128 + q * 4) = pk;
    }
}

// ---------------------------------------------------------------------------
// depthwise 3x3 pad1 on qkv (pm). tile 32x x 4y x 32ch.
// ---------------------------------------------------------------------------
__global__ __launch_bounds__(256) void dw_qkv(
    const bf16* __restrict__ in, const float* __restrict__ w, bf16* __restrict__ out)
{
    __shared__ short ins[6 * 34 * 40];
    const int t = threadIdx.x;
    const int cg = blockIdx.y, b = blockIdx.z;
    const int x0 = (blockIdx.x & 3) * 32, y0 = (blockIdx.x >> 2) * 4;
    for (int g = t; g < 816; g += 256) {
        int r = g / 136, rm = g % 136, xx = rm >> 2, c8 = rm & 3;
        int gy = y0 - 1 + r, gx = x0 - 1 + xx;
        s16x8 v = s16x8{0,0,0,0,0,0,0,0};
        if (gy >= 0 && gy < 128 && gx >= 0 && gx < 128)
            v = *(const s16x8*)((const short*)in +
                  ((size_t)(b << 14) + (gy << 7) + gx) * 384 + cg * 32 + c8 * 8);
        *(s16x8*)&ins[(r * 34 + xx) * 40 + c8 * 8] = v;
    }
    __syncthreads();
    const int x = t >> 3, cq = t & 7, cl = cq * 4, ch = cg * 32 + cl;
    float wv[4][9];
#pragma unroll
    for (int cc = 0; cc < 4; cc++)
#pragma unroll
        for (int k = 0; k < 9; k++) wv[cc][k] = w[(ch + cc) * 9 + k];
#pragma unroll
    for (int yy = 0; yy < 4; yy++) {
        fx4 a = fx4{0.f, 0.f, 0.f, 0.f};
#pragma unroll
        for (int dy = 0; dy < 3; dy++)
#pragma unroll
            for (int dx = 0; dx < 3; dx++) {
                s16x4 v = *(const s16x4*)&ins[((yy + dy) * 34 + x + dx) * 40 + cl];
#pragma unroll
                for (int cc = 0; cc < 4; cc++)
                    a[cc] = fmaf(wv[cc][dy * 3 + dx], uu2f((unsigned short)v[cc]), a[cc]);
            }
        s16x4 pk;
#pragma unroll
        for (int cc = 0; cc < 4; cc++) pk[cc] = (short)f2us(a[cc]);
        *(s16x4*)((short*)out + ((size_t)(b << 14) + ((y0 + yy) << 7) + x0 + x) * 384 + ch) = pk;
    }
}

// ---------------------------------------------------------------------------
// FFN depthwise 3x3 + GELU gate (pm): g[n][c] = gelu(dw_c(h1)) * dw_{c+340}(h1)
// ---------------------------------------------------------------------------
__global__ __launch_bounds__(256) void dw_gate(
    const bf16* __restrict__ h1, const float* __restrict__ w, bf16* __restrict__ g)
{
    __shared__ short in1[6 * 34 * 40];
    __shared__ short in2[6 * 34 * 40];
    const int t = threadIdx.x;
    const int cg = blockIdx.y, b = blockIdx.z;
    const int x0 = (blockIdx.x & 3) * 32, y0 = (blockIdx.x >> 2) * 4;
    for (int gg = t; gg < 1632; gg += 256) {
        int half = gg >= 816;
        int g2 = gg - half * 816;
        int r = g2 / 136, rm = g2 % 136, xx = rm >> 2, c8 = rm & 3;
        int gy = y0 - 1 + r, gx = x0 - 1 + xx;
        int chb = cg * 32 + c8 * 8 + (half ? 340 : 0);
        int lim = half ? 680 : 340;
        s16x8 v = s16x8{0,0,0,0,0,0,0,0};
        if (gy >= 0 && gy < 128 && gx >= 0 && gx < 128) {
            const short* base = (const short*)h1 +
                ((size_t)(b << 14) + (gy << 7) + gx) * 680 + chb;
            if (chb + 8 <= lim) {
                s16x4 lo = *(const s16x4*)base;
                s16x4 hi = *(const s16x4*)(base + 4);
#pragma unroll
                for (int e = 0; e < 4; e++) { v[e] = lo[e]; v[e + 4] = hi[e]; }
            } else {
#pragma unroll
                for (int e = 0; e < 8; e++) v[e] = (chb + e < lim) ? base[e] : (short)0;
            }
        }
        short* dst = half ? in2 : in1;
        *(s16x8*)&dst[(r * 34 + xx) * 40 + c8 * 8] = v;
    }
    __syncthreads();
    const int x = t >> 3, cq = t & 7, cl = cq * 4;
    const int c = cg * 32 + cl;   // out channel base, [0,352)
    float w1[4][9], w2[4][9];
#pragma unroll
    for (int cc = 0; cc < 4; cc++) {
        int cr = c + cc;
        bool ok = cr < 340;
#pragma unroll
        for (int k = 0; k < 9; k++) {
            w1[cc][k] = ok ? w[cr * 9 + k] : 0.f;
            w2[cc][k] = ok ? w[(cr + 340) * 9 + k] : 0.f;
        }
    }
#pragma unroll
    for (int yy = 0; yy < 4; yy++) {
        fx4 a1 = fx4{0.f,0.f,0.f,0.f}, a2 = fx4{0.f,0.f,0.f,0.f};
#pragma unroll
        for (int dy = 0; dy < 3; dy++)
#pragma unroll
            for (int dx = 0; dx < 3; dx++) {
                int off = ((yy + dy) * 34 + x + dx) * 40 + cl;
                s16x4 v1 = *(const s16x4*)&in1[off];
                s16x4 v2 = *(const s16x4*)&in2[off];
#pragma unroll
                for (int cc = 0; cc < 4; cc++) {
                    a1[cc] = fmaf(w1[cc][dy * 3 + dx], uu2f((unsigned short)v1[cc]), a1[cc]);
                    a2[cc] = fmaf(w2[cc][dy * 3 + dx], uu2f((unsigned short)v2[cc]), a2[cc]);
                }
            }
        s16x4 pk;
#pragma unroll
        for (int cc = 0; cc < 4; cc++) {
            float ge = 0.5f * a1[cc] * (1.f + erff(a1[cc] * 0.70710678118f));
            float val = (c + cc < 340) ? ge * a2[cc] : 0.f;
            pk[cc] = (short)f2us(val);
        }
        *(s16x4*)((short*)g + ((size_t)(b << 14) + ((y0 + yy) << 7) + x0 + x) * 352 + c) = pk;
    }
}

// ---------------------------------------------------------------------------
// sum of squares per (b, qk-channel) -> nbuf[b*256+c]   (pre-zeroed)
// ---------------------------------------------------------------------------
__global__ __launch_bounds__(256) void rownorm(const bf16* __restrict__ qkv,
                                               float* __restrict__ nbuf)
{
    int b = blockIdx.x >> 5, chk = blockIdx.x & 31, c = threadIdx.x;
    const short* base = (const short*)qkv + ((size_t)(b * 16384 + chk * 512)) * 384 + c;
    float ss = 0.f;
#pragma unroll 4
    for (int i = 0; i < 512; i++) {
        float v = uu2f((unsigned short)base[(size_t)i * 384]);
        ss = fmaf(v, v, ss);
    }
    atomicAdd(&nbuf[b * 256 + c], ss);
}

// ---------------------------------------------------------------------------
// raw scores S[bh][i][j] += sum_{n chunk} q[n][i]*k[n][j]   (S pre-zeroed)
// ---------------------------------------------------------------------------
__global__ __launch_bounds__(256) void scores(const bf16* __restrict__ qkv,
                                              float* __restrict__ S)
{
    __shared__ short qs[256 * 40];
    __shared__ short ks2[256 * 40];
    const int t = threadIdx.x;
    const int bh = blockIdx.x, b = bh >> 2, h = bh & 3;
    const int n0 = blockIdx.y * 256;
    {
        const short* src = (const short*)qkv + ((size_t)(b * 16384 + n0 + t)) * 384 + h * 32;
#pragma unroll
        for (int i = 0; i < 4; i++) {
            *(s16x8*)&qs[t * 40 + i * 8]  = *(const s16x8*)(src + i * 8);
            *(s16x8*)&ks2[t * 40 + i * 8] = *(const s16x8*)(src + 128 + i * 8);
        }
    }
    __syncthreads();
    const int i2 = t >> 4, j16 = t & 15;
    float a00 = 0.f, a01 = 0.f, a10 = 0.f, a11 = 0.f;
    for (int n = 0; n < 256; n++) {
        unsigned qq = *(const unsigned*)&qs[n * 40 + i2 * 2];
        unsigned kk = *(const unsigned*)&ks2[n * 40 + j16 * 2];
        float q0 = uu2f((unsigned short)(qq & 0xffff)), q1 = uu2f((unsigned short)(qq >> 16));
        float k0 = uu2f((unsigned short)(kk & 0xffff)), k1 = uu2f((unsigned short)(kk >> 16));
        a00 = fmaf(q0, k0, a00); a01 = fmaf(q0, k1, a01);
        a10 = fmaf(q1, k0, a10); a11 = fmaf(q1, k1, a11);
    }
    float* base = S + (size_t)bh * 1024;
    atomicAdd(&base[(i2 * 2 + 0) * 32 + j16 * 2 + 0], a00);
    atomicAdd(&base[(i2 * 2 + 0) * 32 + j16 * 2 + 1], a01);
    atomicAdd(&base[(i2 * 2 + 1) * 32 + j16 * 2 + 0], a10);
    atomicAdd(&base[(i2 * 2 + 1) * 32 + j16 * 2 + 1], a11);
}

// softmax with temperature and q/k norms; in-place on S
__global__ void softmax_k(float* __restrict__ S, const float* __restrict__ nbuf,
                          const float* __restrict__ temp)
{
    __shared__ float invk[32];
    int bh = blockIdx.x, b = bh >> 2, h = bh & 3, i = threadIdx.x;
    invk[i] = 1.f / fmaxf(sqrtf(nbuf[b * 256 + 128 + h * 32 + i]), 1e-12f);
    __syncthreads();
    float ti = temp[h] / fmaxf(sqrtf(nbuf[b * 256 + h * 32 + i]), 1e-12f);
    float* row = S + (size_t)bh * 1024 + i * 32;
    float vals[32], m = -1e30f;
#pragma unroll
    for (int j = 0; j < 32; j++) { vals[j] = row[j] * ti * invk[j]; m = fmaxf(m, vals[j]); }
    float s = 0.f;
#pragma unroll
    for (int j = 0; j < 32; j++) { vals[j] = expf(vals[j] - m); s += vals[j]; }
    float r = 1.f / s;
#pragma unroll
    for (int j = 0; j < 32; j++) row[j] = vals[j] * r;
}

// atto[n][h*32+c] = sum_d attn[c][d] * v[n][d]
__global__ __launch_bounds__(256) void attnapply(const bf16* __restrict__ qkv,
                                                 const float* __restrict__ S,
                                                 bf16* __restrict__ atto)
{
    __shared__ float sa[1024];
    const int t = threadIdx.x;
    const int bh = blockIdx.x, b = bh >> 2, h = bh & 3;
    const int n0 = blockIdx.y * 1024;
    for (int i = t; i < 1024; i += 256) sa[i] = S[(size_t)bh * 1024 + i];
    __syncthreads();
#pragma unroll
    for (int pp = 0; pp < 4; pp++) {
        int n = n0 + (t << 2) + pp;
        const short* vs = (const short*)qkv + ((size_t)(b * 16384) + n) * 384 + 256 + h * 32;
        float v[32];
#pragma unroll
        for (int i = 0; i < 4; i++) {
            s16x8 vv = *(const s16x8*)(vs + i * 8);
#pragma unroll
            for (int e = 0; e < 8; e++) v[i * 8 + e] = uu2f((unsigned short)vv[e]);
        }
        short ov[32];
#pragma unroll
        for (int c = 0; c < 32; c++) {
            const fx4* row = (const fx4*)&sa[c * 32];
            float a = 0.f;
#pragma unroll
            for (int d4 = 0; d4 < 8; d4++) {
                fx4 w4 = row[d4];
                a += w4[0] * v[d4 * 4] + w4[1] * v[d4 * 4 + 1] +
                     w4[2] * v[d4 * 4 + 2] + w4[3] * v[d4 * 4 + 3];
            }
            ov[c] = (short)f2us(a);
        }
        short* dst = (short*)atto + ((size_t)(b * 16384) + n) * 128 + h * 32;
#pragma unroll
        for (int i = 0; i < 4; i++) *(s16x8*)(dst + i * 8) = *(s16x8*)&ov[i * 8];
    }
}

// ---------------------------------------------------------------------------
extern "C" void kernel_launch(void* const* d_in, const int* in_sizes, int n_in,
                              void* d_out, int out_size, void* d_ws, size_t ws_size,
                              hipStream_t stream)
{
    const float* x_main      = (const float*)d_in[0];
    const float* x_prev      = (const float*)d_in[1];
    const float* x_next      = (const float*)d_in[2];
    const float* alpha_down  = (const float*)d_in[3];
    const float* alpha_up    = (const float*)d_in[4];
    const float* down_w      = (const float*)d_in[5];
    const float* up_w        = (const float*)d_in[6];
    const float* norm1_w     = (const float*)d_in[7];
    const float* norm1_b     = (const float*)d_in[8];
    const float* temperature = (const float*)d_in[9];
    const float* qkv_w       = (const float*)d_in[10];
    const float* qkv_dw_w    = (const float*)d_in[11];
    const float* proj_w      = (const float*)d_in[12];
    const float* norm2_w     = (const float*)d_in[13];
    const float* norm2_b     = (const float*)d_in[14];
    const float* ffn_in_w    = (const float*)d_in[15];
    const float* ffn_dw_w    = (const float*)d_in[16];
    const float* ffn_out_w   = (const float*)d_in[17];
    float* out = (float*)d_out;
    (void)in_sizes; (void)n_in; (void)out_size; (void)ws_size;

    char* ws = (char*)d_ws;
    bf16* xnext_pm = (bf16*)(ws + OFF_XNEXT);
    bf16* up_pm    = (bf16*)(ws + OFF_UP);
    bf16* xprev_pm = (bf16*)(ws + OFF_XPREV);
    bf16* qkv_a    = (bf16*)(ws + OFF_SL1);
    bf16* h1       = (bf16*)(ws + OFF_SL1);
    bf16* qkv_b    = (bf16*)(ws + OFF_SL2);
    bf16* gbuf     = (bf16*)(ws + OFF_SL2);
    bf16* y1       = (bf16*)(ws + OFF_SL3);
    bf16* atto     = (bf16*)(ws + OFF_SL3);
    bf16* x_pm     = (bf16*)(ws + OFF_SL4);
    bf16* y2       = (bf16*)(ws + OFF_SL5);
    bf16* Wup      = (bf16*)(ws + OFF_WUP);
    bf16* Wqkv     = (bf16*)(ws + OFF_WQKV);
    bf16* Wprj     = (bf16*)(ws + OFF_WPRJ);
    bf16* Wfin     = (bf16*)(ws + OFF_WFIN);
    bf16* Wfout    = (bf16*)(ws + OFF_WFOUT);
    float* wdwn    = (float*)(ws + OFF_WDWN);
    float* nbuf    = (float*)(ws + OFF_NBUF);
    float* Sbuf    = (float*)(ws + OFF_S);

    // zero nbuf + S (adjacent)
    hipMemsetAsync(nbuf, 0, 8192 + 131072, stream);

    // weight conversions
    conv_pad<<<dim3(512), 256, 0, stream>>>(up_w, Wup, 512, 256, 512, 256);
    conv_pad<<<dim3(192), 256, 0, stream>>>(qkv_w, Wqkv, 384, 128, 384, 128);
    conv_pad<<<dim3(64), 256, 0, stream>>>(proj_w, Wprj, 128, 128, 128, 128);
    conv_pad<<<dim3(384), 256, 0, stream>>>(ffn_in_w, Wfin, 680, 128, MFI, 128);
    conv_pad<<<dim3(176), 256, 0, stream>>>(ffn_out_w, Wfout, 128, 340, 128, KFF);
    wdwn_perm<<<dim3(288), 256, 0, stream>>>(down_w, wdwn);

    // transposes to pixel-major
    transpose_c2p<<<dim3(128, 8, BATCH), 256, 0, stream>>>(x_next, xnext_pm, 256, 4096);
    transpose_c2p<<<dim3(2048, 2, BATCH), 256, 0, stream>>>(x_prev, xprev_pm, 64, 65536);

    // up 1x1 conv (GEMM): up_pm[b][4096][512]
    gemm_mfma<0><<<dim3(32, 4, BATCH), 256, 0, stream>>>(
        xnext_pm, Wup, 256, 4096, 512, 512, up_pm,
        nullptr, nullptr, nullptr, nullptr, nullptr, nullptr);

    // fused down-conv + residual + shuffle + LN1 -> y1
    fuse_down_ln<<<dim3(4, 128, BATCH), 256, 0, stream>>>(
        xprev_pm, x_main, up_pm, wdwn, alpha_down, alpha_up, norm1_w, norm1_b, y1);

    // qkv 1x1 (GEMM): qkv_a[b][16384][384]
    gemm_mfma<0><<<dim3(128, 3, BATCH), 256, 0, stream>>>(
        y1, Wqkv, 128, NPIX, 384, 384, qkv_a,
        nullptr, nullptr, nullptr, nullptr, nullptr, nullptr);

    // depthwise 3x3 -> qkv_b
    dw_qkv<<<dim3(128, 12, BATCH), 256, 0, stream>>>(qkv_a, qkv_dw_w, qkv_b);

    // q/k norms, scores, softmax, attn@v
    rownorm<<<dim3(256), 256, 0, stream>>>(qkv_b, nbuf);
    scores<<<dim3(32, 64), 256, 0, stream>>>(qkv_b, Sbuf);
    softmax_k<<<dim3(32), 32, 0, stream>>>(Sbuf, nbuf, temperature);
    attnapply<<<dim3(32, 16), 256, 0, stream>>>(qkv_b, Sbuf, atto);

    // proj GEMM + residual + fused LN2 -> x_pm (bf16) + y2
    gemm_mfma<1><<<dim3(128, 1, BATCH), 256, 0, stream>>>(
        atto, Wprj, 128, NPIX, 128, 128, y2,
        x_main, x_pm, norm2_w, norm2_b, nullptr, nullptr);

    // ffn_in GEMM -> h1[b][16384][680]
    gemm_mfma<0><<<dim3(128, 6, BATCH), 256, 0, stream>>>(
        y2, Wfin, 128, NPIX, 680, 680, h1,
        nullptr, nullptr, nullptr, nullptr, nullptr, nullptr);

    // dw + gelu gate -> g[b][16384][352]
    dw_gate<<<dim3(128, 11, BATCH), 256, 0, stream>>>(h1, ffn_dw_w, gbuf);

    // ffn_out GEMM + residual -> out (NCHW f32)
    gemm_mfma<2><<<dim3(128, 1, BATCH), 256, 0, stream>>>(
        gbuf, Wfout, KFF, NPIX, 128, 128, nullptr,
        nullptr, nullptr, nullptr, nullptr, x_pm, out);
}

// Round 3
// 692.121 us; speedup vs baseline: 3.3235x; 1.4019x over previous
//
#include <hip/hip_runtime.h>
#include <hip/hip_bf16.h>
#include <math.h>

using bf16 = __hip_bfloat16;
#define DEV static __device__ __forceinline__

typedef float  fx4   __attribute__((ext_vector_type(4)));
typedef short  s16x8 __attribute__((ext_vector_type(8)));
typedef short  s16x4 __attribute__((ext_vector_type(4)));
typedef __bf16 bfx8  __attribute__((ext_vector_type(8)));

constexpr int BATCH = 8;
constexpr int CDIM  = 128;
constexpr int NPIX  = 16384;      // 128x128
constexpr int HIDF  = 340;
constexpr int KFF   = 352;        // padded K for ffn_out
constexpr int MFI   = 768;        // padded M for ffn_in (true 680)

DEV float uu2f(unsigned short u) { return __uint_as_float(((unsigned)u) << 16); }
DEV unsigned short f2us(float f) { bf16 h = __float2bfloat16(f); return *(unsigned short*)&h; }
DEV float bl2f(bf16 v) { return __bfloat162float(v); }

// ---------------- workspace layout (bytes) ----------------
constexpr size_t OFF_SL1   = 0;                    // {xnext_pm,up_pm,xprev_pm} -> qkv_a -> h1
constexpr size_t OFF_XNEXT = OFF_SL1;              // 16.78MB
constexpr size_t OFF_UP    = OFF_SL1 + 16777216;   // 33.55MB
constexpr size_t OFF_XPREV = OFF_SL1 + 50331648;   // 67.1MB
constexpr size_t SZ_SL1    = 178257920;            // h1 = 8*16384*680*2
constexpr size_t OFF_SL2   = OFF_SL1 + SZ_SL1;     // qkv_b -> g
constexpr size_t OFF_SL3   = OFF_SL2 + 100663296;  // y1 -> atto
constexpr size_t OFF_SL4   = OFF_SL3 + 33554432;   // x (bf16 pm)
constexpr size_t OFF_SL5   = OFF_SL4 + 33554432;   // y2
constexpr size_t OFF_W     = OFF_SL5 + 33554432;
constexpr size_t OFF_WUP   = OFF_W;                // 512*256*2
constexpr size_t OFF_WQKV  = OFF_W +  262144;      // 384*128*2
constexpr size_t OFF_WPRJ  = OFF_W +  360448;      // 128*128*2
constexpr size_t OFF_WFIN  = OFF_W +  393216;      // 768*128*2
constexpr size_t OFF_WFOUT = OFF_W +  589824;      // 128*352*2
constexpr size_t OFF_WTAP  = OFF_W +  679936;      // 9*128*64*2 = 147456 bf16
constexpr size_t OFF_ZP    = OFF_W +  827392;      // 256B zero page
constexpr size_t OFF_NBUF  = OFF_W +  974848;      // 8*256*4
constexpr size_t OFF_S     = OFF_W +  983040;      // 32*1024*4

// ---------------------------------------------------------------------------
// generic f32 -> bf16 weight convert with zero padding
// ---------------------------------------------------------------------------
__global__ void conv_pad(const float* __restrict__ src, bf16* __restrict__ dst,
                         int Rs, int Cs, int Rd, int Cd)
{
    int n = Rd * Cd;
    for (int i = blockIdx.x * 256 + threadIdx.x; i < n; i += gridDim.x * 256) {
        int r = i / Cd, c = i % Cd;
        dst[i] = (r < Rs && c < Cs) ? __float2bfloat16(src[r * Cs + c]) : bf16(0.f);
    }
}

// down_w [128co][64ci][9] f32 -> wtap [9][128co][64ci] bf16
__global__ void wtap_prep(const float* __restrict__ src, bf16* __restrict__ dst)
{
    int i = blockIdx.x * 256 + threadIdx.x;
    if (i >= 9 * 128 * 64) return;
    int tap = i >> 13, rm = i & 8191, co = rm >> 6, ci = rm & 63;
    dst[i] = __float2bfloat16(src[(co * 64 + ci) * 9 + tap]);
}

// NCHW f32 -> pixel-major bf16 transpose
__global__ __launch_bounds__(256) void transpose_c2p(
    const float* __restrict__ in, bf16* __restrict__ out, int C, int HW)
{
    __shared__ float ts[32][33];
    int hw0 = blockIdx.x * 32, c0 = blockIdx.y * 32, b = blockIdx.z;
    int rl = threadIdx.x >> 5, cl = threadIdx.x & 31;
#pragma unroll
    for (int i = 0; i < 4; i++)
        ts[rl + i * 8][cl] = in[((size_t)b * C + c0 + rl + i * 8) * HW + hw0 + cl];
    __syncthreads();
#pragma unroll
    for (int i = 0; i < 4; i++)
        out[((size_t)b * HW + hw0 + rl + i * 8) * C + c0 + cl] =
            __float2bfloat16(ts[cl][rl + i * 8]);
}

// ---------------------------------------------------------------------------
// MFMA GEMM: D[b][n][co] = sum_k Act[b][n][k] * Wt[co][k]
// tile 128n x 128co, BK=32, 4 waves (2x2), 16x16x32 bf16 MFMA.
// EPI 0: store bf16 pm; EPI 1: residual+LN2; EPI 2: residual -> f32 NCHW
// ---------------------------------------------------------------------------
template <int EPI>
__global__ __launch_bounds__(256) void gemm_mfma(
    const bf16* __restrict__ Act, const bf16* __restrict__ Wt,
    int K, int Npb, int Mtrue, int Mstride,
    bf16* __restrict__ outB,
    const float* __restrict__ xmain, bf16* __restrict__ x_out,
    const float* __restrict__ nw, const float* __restrict__ nb,
    const bf16* __restrict__ xres, float* __restrict__ outF)
{
    __shared__ short As[128 * 32];
    __shared__ short Bs[128 * 32];
    const int t = threadIdx.x;
    const int w = t >> 6, lane = t & 63;
    const int wr = w >> 1, wc = w & 1;
    const int lr = lane & 15, lg = lane >> 4;
    const int n0 = blockIdx.x * 128;
    const int m0 = blockIdx.y * 128;
    const int b  = blockIdx.z;
    const bf16* Abase = Act + (size_t)b * Npb * K;

    fx4 acc[4][4];
#pragma unroll
    for (int i = 0; i < 4; i++)
#pragma unroll
        for (int j = 0; j < 4; j++) acc[i][j] = fx4{0.f, 0.f, 0.f, 0.f};

    const int f0 = w * 128 + lane, f1 = f0 + 64;
    const int r0 = f0 >> 2, c0 = (f0 & 3) * 8;
    const int r1 = f1 >> 2, c1 = (f1 & 3) * 8;

    for (int ks = 0; ks < K; ks += 32) {
        __builtin_amdgcn_global_load_lds(
            (const __attribute__((address_space(1))) void*)(Abase + (size_t)(n0 + r0) * K + ks + c0),
            (__attribute__((address_space(3))) void*)(As + w * 1024), 16, 0, 0);
        __builtin_amdgcn_global_load_lds(
            (const __attribute__((address_space(1))) void*)(Abase + (size_t)(n0 + r1) * K + ks + c1),
            (__attribute__((address_space(3))) void*)(As + w * 1024 + 512), 16, 0, 0);
        __builtin_amdgcn_global_load_lds(
            (const __attribute__((address_space(1))) void*)(Wt + (size_t)(m0 + r0) * K + ks + c0),
            (__attribute__((address_space(3))) void*)(Bs + w * 1024), 16, 0, 0);
        __builtin_amdgcn_global_load_lds(
            (const __attribute__((address_space(1))) void*)(Wt + (size_t)(m0 + r1) * K + ks + c1),
            (__attribute__((address_space(3))) void*)(Bs + w * 1024 + 512), 16, 0, 0);
        __syncthreads();
        bfx8 af[4], bw[4];
#pragma unroll
        for (int mi = 0; mi < 4; mi++)
            af[mi] = __builtin_bit_cast(bfx8,
                *(const s16x8*)&As[(wr * 64 + mi * 16 + lr) * 32 + lg * 8]);
#pragma unroll
        for (int ni = 0; ni < 4; ni++)
            bw[ni] = __builtin_bit_cast(bfx8,
                *(const s16x8*)&Bs[(wc * 64 + ni * 16 + lr) * 32 + lg * 8]);
#pragma unroll
        for (int mi = 0; mi < 4; mi++)
#pragma unroll
            for (int ni = 0; ni < 4; ni++)
                acc[mi][ni] = __builtin_amdgcn_mfma_f32_16x16x32_bf16(
                    af[mi], bw[ni], acc[mi][ni], 0, 0, 0);
        __syncthreads();
    }

    if (EPI == 0) {
#pragma unroll
        for (int mi = 0; mi < 4; mi++)
#pragma unroll
            for (int ni = 0; ni < 4; ni++) {
                int co = m0 + wc * 64 + ni * 16 + lr;
                if (co < Mtrue) {
#pragma unroll
                    for (int r = 0; r < 4; r++) {
                        int px = n0 + wr * 64 + mi * 16 + lg * 4 + r;
                        outB[((size_t)b * Npb + px) * Mstride + co] =
                            __float2bfloat16(acc[mi][ni][r]);
                    }
                }
            }
    } else if (EPI == 1) {
        float xv[4][4][4];
#pragma unroll
        for (int mi = 0; mi < 4; mi++)
#pragma unroll
            for (int ni = 0; ni < 4; ni++) {
                int co = wc * 64 + ni * 16 + lr;
                fx4 x4 = *(const fx4*)&xmain[((size_t)b * 128 + co) * 16384 +
                                             n0 + wr * 64 + mi * 16 + lg * 4];
#pragma unroll
                for (int r = 0; r < 4; r++) xv[mi][ni][r] = x4[r] + acc[mi][ni][r];
            }
        __shared__ float ps[2][128];
        __shared__ float pss[2][128];
#pragma unroll
        for (int mi = 0; mi < 4; mi++)
#pragma unroll
            for (int r = 0; r < 4; r++) {
                float s = 0.f, s2 = 0.f;
#pragma unroll
                for (int ni = 0; ni < 4; ni++) {
                    float v = xv[mi][ni][r]; s += v; s2 += v * v;
                }
#pragma unroll
                for (int m = 1; m < 16; m <<= 1) {
                    s  += __shfl_xor(s, m);
                    s2 += __shfl_xor(s2, m);
                }
                if (lr == 0) {
                    int row = wr * 64 + mi * 16 + lg * 4 + r;
                    ps[wc][row] = s; pss[wc][row] = s2;
                }
            }
        __syncthreads();
        float nwv[4], nbv[4];
#pragma unroll
        for (int ni = 0; ni < 4; ni++) {
            int co = wc * 64 + ni * 16 + lr;
            nwv[ni] = nw[co]; nbv[ni] = nb[co];
        }
#pragma unroll
        for (int mi = 0; mi < 4; mi++)
#pragma unroll
            for (int r = 0; r < 4; r++) {
                int row = wr * 64 + mi * 16 + lg * 4 + r;
                float s  = ps[0][row] + ps[1][row];
                float s2 = pss[0][row] + pss[1][row];
                float mu = s * (1.f / 128.f);
                float var = s2 * (1.f / 128.f) - mu * mu;
                float rstd = rsqrtf(var + 1e-5f);
                size_t px = (size_t)b * 16384 + n0 + row;
#pragma unroll
                for (int ni = 0; ni < 4; ni++) {
                    int co = wc * 64 + ni * 16 + lr;
                    float v = xv[mi][ni][r];
                    x_out[px * 128 + co] = __float2bfloat16(v);
                    outB[px * 128 + co] = __float2bfloat16((v - mu) * rstd * nwv[ni] + nbv[ni]);
                }
            }
    } else {  // EPI 2
#pragma unroll
        for (int mi = 0; mi < 4; mi++)
#pragma unroll
            for (int ni = 0; ni < 4; ni++) {
                int co = wc * 64 + ni * 16 + lr;
                int pxb = n0 + wr * 64 + mi * 16 + lg * 4;
                fx4 o;
#pragma unroll
                for (int r = 0; r < 4; r++)
                    o[r] = acc[mi][ni][r] +
                           bl2f(xres[((size_t)b * 16384 + pxb + r) * 128 + co]);
                *(fx4*)&outF[((size_t)b * 128 + co) * 16384 + pxb] = o;
            }
    }
}

// ---------------------------------------------------------------------------
// down-conv(3x3,s2) as 9-tap MFMA GEMM + residual + pixel-shuffle + LN1 -> y1
// block = one output row y (128 px) x 128 co. K = 9 taps x 64 ci.
// A-tile gathered per tap via per-lane global_load_lds source addressing;
// OOB lanes read a zeroed global page.
// ---------------------------------------------------------------------------
__global__ __launch_bounds__(256) void down_mfma_ln(
    const bf16* __restrict__ xprev_pm,   // [b][65536][64]
    const float* __restrict__ xmain,     // NCHW f32
    const bf16* __restrict__ up_pm,      // [b][4096][512]
    const bf16* __restrict__ wtap,       // [9][128co][64ci]
    const float* __restrict__ alpha_d, const float* __restrict__ alpha_u,
    const float* __restrict__ n1w, const float* __restrict__ n1b,
    const bf16* __restrict__ zeropage,
    bf16* __restrict__ y1)               // [b][16384][128]
{
    __shared__ short As[128 * 64];
    __shared__ short Bs[128 * 64];
    __shared__ float ps[2][128];
    __shared__ float pss[2][128];
    const int t = threadIdx.x;
    const int w = t >> 6, lane = t & 63;
    const int wr = w >> 1, wc = w & 1;
    const int lr = lane & 15, lg = lane >> 4;
    const int y = blockIdx.x;
    const int b = blockIdx.y;

    // staging: wave w covers LDS bytes [4096w,4096w+4096), 4 issues of 1KB
    const int srow0 = 32 * w + (lane >> 3);   // + 8*i
    const int sci8  = lane & 7;
    const short* wtbase = (const short*)wtap;

    fx4 acc[4][4];
#pragma unroll
    for (int i = 0; i < 4; i++)
#pragma unroll
        for (int j = 0; j < 4; j++) acc[i][j] = fx4{0.f, 0.f, 0.f, 0.f};

#pragma unroll
    for (int tap = 0; tap < 9; tap++) {
        const int dy = tap / 3, dx = tap % 3;
        const int iy = 2 * y - 1 + dy;
        const bool rowok = (iy >= 0) && (iy < 256);
        const short* arow = (const short*)xprev_pm +
                            (((size_t)b * 65536 + (size_t)iy * 256) * 64);
#pragma unroll
        for (int i = 0; i < 4; i++) {
            int row = srow0 + 8 * i;
            int ix = 2 * row - 1 + dx;
            const short* src = (rowok && ix >= 0 && ix < 256)
                                 ? (arow + (size_t)ix * 64 + sci8 * 8)
                                 : (const short*)zeropage;
            __builtin_amdgcn_global_load_lds(
                (const __attribute__((address_space(1))) void*)src,
                (__attribute__((address_space(3))) void*)(As + w * 2048 + i * 512), 16, 0, 0);
            __builtin_amdgcn_global_load_lds(
                (const __attribute__((address_space(1))) void*)
                    (wtbase + tap * 8192 + w * 2048 + i * 512 + lane * 8),
                (__attribute__((address_space(3))) void*)(Bs + w * 2048 + i * 512), 16, 0, 0);
        }
        __syncthreads();
        bfx8 af[4][2], bw[4][2];
#pragma unroll
        for (int mi = 0; mi < 4; mi++)
#pragma unroll
            for (int ks = 0; ks < 2; ks++)
                af[mi][ks] = __builtin_bit_cast(bfx8,
                    *(const s16x8*)&As[(wr * 64 + mi * 16 + lr) * 64 + ks * 32 + lg * 8]);
#pragma unroll
        for (int ni = 0; ni < 4; ni++)
#pragma unroll
            for (int ks = 0; ks < 2; ks++)
                bw[ni][ks] = __builtin_bit_cast(bfx8,
                    *(const s16x8*)&Bs[(wc * 64 + ni * 16 + lr) * 64 + ks * 32 + lg * 8]);
#pragma unroll
        for (int mi = 0; mi < 4; mi++)
#pragma unroll
            for (int ni = 0; ni < 4; ni++)
#pragma unroll
                for (int ks = 0; ks < 2; ks++)
                    acc[mi][ni] = __builtin_amdgcn_mfma_f32_16x16x32_bf16(
                        af[mi][ks], bw[ni][ks], acc[mi][ni], 0, 0, 0);
        __syncthreads();
    }

    // ---- epilogue: f = x_main + ad*conv + au*up ; LN over co -> y1 ----
    const float ad = alpha_d[0], au = alpha_u[0];
    const int n2base = (y >> 1) * 64;
    const int chb2 = (y & 1) * 2;
    float fv[4][4][4];
#pragma unroll
    for (int mi = 0; mi < 4; mi++) {
        const int x0 = wr * 64 + mi * 16 + lg * 4;
#pragma unroll
        for (int ni = 0; ni < 4; ni++) {
            const int co = wc * 64 + ni * 16 + lr;
            fx4 xm = *(const fx4*)&xmain[(((size_t)b * 128 + co) * 128 + y) * 128 + x0];
            const short* uprow = (const short*)up_pm +
                ((size_t)b * 4096 + n2base + (x0 >> 1)) * 512 + co * 4 + chb2;
            unsigned up01 = *(const unsigned*)uprow;
            unsigned up23 = *(const unsigned*)(uprow + 512);
            fv[mi][ni][0] = xm[0] + ad * acc[mi][ni][0] + au * uu2f((unsigned short)(up01 & 0xffff));
            fv[mi][ni][1] = xm[1] + ad * acc[mi][ni][1] + au * uu2f((unsigned short)(up01 >> 16));
            fv[mi][ni][2] = xm[2] + ad * acc[mi][ni][2] + au * uu2f((unsigned short)(up23 & 0xffff));
            fv[mi][ni][3] = xm[3] + ad * acc[mi][ni][3] + au * uu2f((unsigned short)(up23 >> 16));
        }
    }
#pragma unroll
    for (int mi = 0; mi < 4; mi++)
#pragma unroll
        for (int r = 0; r < 4; r++) {
            float s = 0.f, s2 = 0.f;
#pragma unroll
            for (int ni = 0; ni < 4; ni++) {
                float v = fv[mi][ni][r]; s += v; s2 += v * v;
            }
#pragma unroll
            for (int m = 1; m < 16; m <<= 1) {
                s  += __shfl_xor(s, m);
                s2 += __shfl_xor(s2, m);
            }
            if (lr == 0) {
                int row = wr * 64 + mi * 16 + lg * 4 + r;
                ps[wc][row] = s; pss[wc][row] = s2;
            }
        }
    __syncthreads();
    float nwv[4], nbv[4];
#pragma unroll
    for (int ni = 0; ni < 4; ni++) {
        int co = wc * 64 + ni * 16 + lr;
        nwv[ni] = n1w[co]; nbv[ni] = n1b[co];
    }
#pragma unroll
    for (int mi = 0; mi < 4; mi++)
#pragma unroll
        for (int r = 0; r < 4; r++) {
            int row = wr * 64 + mi * 16 + lg * 4 + r;
            float s  = ps[0][row] + ps[1][row];
            float s2 = pss[0][row] + pss[1][row];
            float mu = s * (1.f / 128.f);
            float var = s2 * (1.f / 128.f) - mu * mu;
            float rstd = rsqrtf(var + 1e-5f);
            size_t px = (size_t)b * 16384 + (size_t)y * 128 + row;
#pragma unroll
            for (int ni = 0; ni < 4; ni++) {
                int co = wc * 64 + ni * 16 + lr;
                ((short*)y1)[px * 128 + co] =
                    (short)f2us((fv[mi][ni][r] - mu) * rstd * nwv[ni] + nbv[ni]);
            }
        }
}

// ---------------------------------------------------------------------------
// depthwise 3x3 pad1 on qkv (pm). tile 32x x 4y x 32ch.
// ---------------------------------------------------------------------------
__global__ __launch_bounds__(256) void dw_qkv(
    const bf16* __restrict__ in, const float* __restrict__ w, bf16* __restrict__ out)
{
    __shared__ short ins[6 * 34 * 40];
    const int t = threadIdx.x;
    const int cg = blockIdx.y, b = blockIdx.z;
    const int x0 = (blockIdx.x & 3) * 32, y0 = (blockIdx.x >> 2) * 4;
    for (int g = t; g < 816; g += 256) {
        int r = g / 136, rm = g % 136, xx = rm >> 2, c8 = rm & 3;
        int gy = y0 - 1 + r, gx = x0 - 1 + xx;
        s16x8 v = s16x8{0,0,0,0,0,0,0,0};
        if (gy >= 0 && gy < 128 && gx >= 0 && gx < 128)
            v = *(const s16x8*)((const short*)in +
                  ((size_t)(b << 14) + (gy << 7) + gx) * 384 + cg * 32 + c8 * 8);
        *(s16x8*)&ins[(r * 34 + xx) * 40 + c8 * 8] = v;
    }
    __syncthreads();
    const int x = t >> 3, cq = t & 7, cl = cq * 4, ch = cg * 32 + cl;
    float wv[4][9];
#pragma unroll
    for (int cc = 0; cc < 4; cc++)
#pragma unroll
        for (int k = 0; k < 9; k++) wv[cc][k] = w[(ch + cc) * 9 + k];
#pragma unroll
    for (int yy = 0; yy < 4; yy++) {
        fx4 a = fx4{0.f, 0.f, 0.f, 0.f};
#pragma unroll
        for (int dy = 0; dy < 3; dy++)
#pragma unroll
            for (int dx = 0; dx < 3; dx++) {
                s16x4 v = *(const s16x4*)&ins[((yy + dy) * 34 + x + dx) * 40 + cl];
#pragma unroll
                for (int cc = 0; cc < 4; cc++)
                    a[cc] = fmaf(wv[cc][dy * 3 + dx], uu2f((unsigned short)v[cc]), a[cc]);
            }
        s16x4 pk;
#pragma unroll
        for (int cc = 0; cc < 4; cc++) pk[cc] = (short)f2us(a[cc]);
        *(s16x4*)((short*)out + ((size_t)(b << 14) + ((y0 + yy) << 7) + x0 + x) * 384 + ch) = pk;
    }
}

// ---------------------------------------------------------------------------
// FFN depthwise 3x3 + GELU gate (pm)
// ---------------------------------------------------------------------------
__global__ __launch_bounds__(256) void dw_gate(
    const bf16* __restrict__ h1, const float* __restrict__ w, bf16* __restrict__ g)
{
    __shared__ short in1[6 * 34 * 40];
    __shared__ short in2[6 * 34 * 40];
    const int t = threadIdx.x;
    const int cg = blockIdx.y, b = blockIdx.z;
    const int x0 = (blockIdx.x & 3) * 32, y0 = (blockIdx.x >> 2) * 4;
    for (int gg = t; gg < 1632; gg += 256) {
        int half = gg >= 816;
        int g2 = gg - half * 816;
        int r = g2 / 136, rm = g2 % 136, xx = rm >> 2, c8 = rm & 3;
        int gy = y0 - 1 + r, gx = x0 - 1 + xx;
        int chb = cg * 32 + c8 * 8 + (half ? 340 : 0);
        int lim = half ? 680 : 340;
        s16x8 v = s16x8{0,0,0,0,0,0,0,0};
        if (gy >= 0 && gy < 128 && gx >= 0 && gx < 128) {
            const short* base = (const short*)h1 +
                ((size_t)(b << 14) + (gy << 7) + gx) * 680 + chb;
            if (chb + 8 <= lim) {
                s16x4 lo = *(const s16x4*)base;
                s16x4 hi = *(const s16x4*)(base + 4);
#pragma unroll
                for (int e = 0; e < 4; e++) { v[e] = lo[e]; v[e + 4] = hi[e]; }
            } else {
#pragma unroll
                for (int e = 0; e < 8; e++) v[e] = (chb + e < lim) ? base[e] : (short)0;
            }
        }
        short* dst = half ? in2 : in1;
        *(s16x8*)&dst[(r * 34 + xx) * 40 + c8 * 8] = v;
    }
    __syncthreads();
    const int x = t >> 3, cq = t & 7, cl = cq * 4;
    const int c = cg * 32 + cl;   // out channel base, [0,352)
    float w1[4][9], w2[4][9];
#pragma unroll
    for (int cc = 0; cc < 4; cc++) {
        int cr = c + cc;
        bool ok = cr < 340;
#pragma unroll
        for (int k = 0; k < 9; k++) {
            w1[cc][k] = ok ? w[cr * 9 + k] : 0.f;
            w2[cc][k] = ok ? w[(cr + 340) * 9 + k] : 0.f;
        }
    }
#pragma unroll
    for (int yy = 0; yy < 4; yy++) {
        fx4 a1 = fx4{0.f,0.f,0.f,0.f}, a2 = fx4{0.f,0.f,0.f,0.f};
#pragma unroll
        for (int dy = 0; dy < 3; dy++)
#pragma unroll
            for (int dx = 0; dx < 3; dx++) {
                int off = ((yy + dy) * 34 + x + dx) * 40 + cl;
                s16x4 v1 = *(const s16x4*)&in1[off];
                s16x4 v2 = *(const s16x4*)&in2[off];
#pragma unroll
                for (int cc = 0; cc < 4; cc++) {
                    a1[cc] = fmaf(w1[cc][dy * 3 + dx], uu2f((unsigned short)v1[cc]), a1[cc]);
                    a2[cc] = fmaf(w2[cc][dy * 3 + dx], uu2f((unsigned short)v2[cc]), a2[cc]);
                }
            }
        s16x4 pk;
#pragma unroll
        for (int cc = 0; cc < 4; cc++) {
            float ge = 0.5f * a1[cc] * (1.f + erff(a1[cc] * 0.70710678118f));
            float val = (c + cc < 340) ? ge * a2[cc] : 0.f;
            pk[cc] = (short)f2us(val);
        }
        *(s16x4*)((short*)g + ((size_t)(b << 14) + ((y0 + yy) << 7) + x0 + x) * 352 + c) = pk;
    }
}

// ---------------------------------------------------------------------------
// sum of squares per (b, qk-channel) -> nbuf[b*256+c]   (pre-zeroed)
// ---------------------------------------------------------------------------
__global__ __launch_bounds__(256) void rownorm(const bf16* __restrict__ qkv,
                                               float* __restrict__ nbuf)
{
    int b = blockIdx.x >> 5, chk = blockIdx.x & 31, c = threadIdx.x;
    const short* base = (const short*)qkv + ((size_t)(b * 16384 + chk * 512)) * 384 + c;
    float ss = 0.f;
#pragma unroll 4
    for (int i = 0; i < 512; i++) {
        float v = uu2f((unsigned short)base[(size_t)i * 384]);
        ss = fmaf(v, v, ss);
    }
    atomicAdd(&nbuf[b * 256 + c], ss);
}

// ---------------------------------------------------------------------------
// raw scores S[bh][i][j] += sum_{n chunk} q[n][i]*k[n][j]   (S pre-zeroed)
// ---------------------------------------------------------------------------
__global__ __launch_bounds__(256) void scores(const bf16* __restrict__ qkv,
                                              float* __restrict__ S)
{
    __shared__ short qs[256 * 40];
    __shared__ short ks2[256 * 40];
    const int t = threadIdx.x;
    const int bh = blockIdx.x, b = bh >> 2, h = bh & 3;
    const int n0 = blockIdx.y * 256;
    {
        const short* src = (const short*)qkv + ((size_t)(b * 16384 + n0 + t)) * 384 + h * 32;
#pragma unroll
        for (int i = 0; i < 4; i++) {
            *(s16x8*)&qs[t * 40 + i * 8]  = *(const s16x8*)(src + i * 8);
            *(s16x8*)&ks2[t * 40 + i * 8] = *(const s16x8*)(src + 128 + i * 8);
        }
    }
    __syncthreads();
    const int i2 = t >> 4, j16 = t & 15;
    float a00 = 0.f, a01 = 0.f, a10 = 0.f, a11 = 0.f;
    for (int n = 0; n < 256; n++) {
        unsigned qq = *(const unsigned*)&qs[n * 40 + i2 * 2];
        unsigned kk = *(const unsigned*)&ks2[n * 40 + j16 * 2];
        float q0 = uu2f((unsigned short)(qq & 0xffff)), q1 = uu2f((unsigned short)(qq >> 16));
        float k0 = uu2f((unsigned short)(kk & 0xffff)), k1 = uu2f((unsigned short)(kk >> 16));
        a00 = fmaf(q0, k0, a00); a01 = fmaf(q0, k1, a01);
        a10 = fmaf(q1, k0, a10); a11 = fmaf(q1, k1, a11);
    }
    float* base = S + (size_t)bh * 1024;
    atomicAdd(&base[(i2 * 2 + 0) * 32 + j16 * 2 + 0], a00);
    atomicAdd(&base[(i2 * 2 + 0) * 32 + j16 * 2 + 1], a01);
    atomicAdd(&base[(i2 * 2 + 1) * 32 + j16 * 2 + 0], a10);
    atomicAdd(&base[(i2 * 2 + 1) * 32 + j16 * 2 + 1], a11);
}

// softmax with temperature and q/k norms; in-place on S
__global__ void softmax_k(float* __restrict__ S, const float* __restrict__ nbuf,
                          const float* __restrict__ temp)
{
    __shared__ float invk[32];
    int bh = blockIdx.x, b = bh >> 2, h = bh & 3, i = threadIdx.x;
    invk[i] = 1.f / fmaxf(sqrtf(nbuf[b * 256 + 128 + h * 32 + i]), 1e-12f);
    __syncthreads();
    float ti = temp[h] / fmaxf(sqrtf(nbuf[b * 256 + h * 32 + i]), 1e-12f);
    float* row = S + (size_t)bh * 1024 + i * 32;
    float vals[32], m = -1e30f;
#pragma unroll
    for (int j = 0; j < 32; j++) { vals[j] = row[j] * ti * invk[j]; m = fmaxf(m, vals[j]); }
    float s = 0.f;
#pragma unroll
    for (int j = 0; j < 32; j++) { vals[j] = expf(vals[j] - m); s += vals[j]; }
    float r = 1.f / s;
#pragma unroll
    for (int j = 0; j < 32; j++) row[j] = vals[j] * r;
}

// atto[n][h*32+c] = sum_d attn[c][d] * v[n][d]
__global__ __launch_bounds__(256) void attnapply(const bf16* __restrict__ qkv,
                                                 const float* __restrict__ S,
                                                 bf16* __restrict__ atto)
{
    __shared__ float sa[1024];
    const int t = threadIdx.x;
    const int bh = blockIdx.x, b = bh >> 2, h = bh & 3;
    const int n0 = blockIdx.y * 1024;
    for (int i = t; i < 1024; i += 256) sa[i] = S[(size_t)bh * 1024 + i];
    __syncthreads();
#pragma unroll
    for (int pp = 0; pp < 4; pp++) {
        int n = n0 + (t << 2) + pp;
        const short* vs = (const short*)qkv + ((size_t)(b * 16384) + n) * 384 + 256 + h * 32;
        float v[32];
#pragma unroll
        for (int i = 0; i < 4; i++) {
            s16x8 vv = *(const s16x8*)(vs + i * 8);
#pragma unroll
            for (int e = 0; e < 8; e++) v[i * 8 + e] = uu2f((unsigned short)vv[e]);
        }
        short ov[32];
#pragma unroll
        for (int c = 0; c < 32; c++) {
            const fx4* row = (const fx4*)&sa[c * 32];
            float a = 0.f;
#pragma unroll
            for (int d4 = 0; d4 < 8; d4++) {
                fx4 w4 = row[d4];
                a += w4[0] * v[d4 * 4] + w4[1] * v[d4 * 4 + 1] +
                     w4[2] * v[d4 * 4 + 2] + w4[3] * v[d4 * 4 + 3];
            }
            ov[c] = (short)f2us(a);
        }
        short* dst = (short*)atto + ((size_t)(b * 16384) + n) * 128 + h * 32;
#pragma unroll
        for (int i = 0; i < 4; i++) *(s16x8*)(dst + i * 8) = *(s16x8*)&ov[i * 8];
    }
}

// ---------------------------------------------------------------------------
extern "C" void kernel_launch(void* const* d_in, const int* in_sizes, int n_in,
                              void* d_out, int out_size, void* d_ws, size_t ws_size,
                              hipStream_t stream)
{
    const float* x_main      = (const float*)d_in[0];
    const float* x_prev      = (const float*)d_in[1];
    const float* x_next      = (const float*)d_in[2];
    const float* alpha_down  = (const float*)d_in[3];
    const float* alpha_up    = (const float*)d_in[4];
    const float* down_w      = (const float*)d_in[5];
    const float* up_w        = (const float*)d_in[6];
    const float* norm1_w     = (const float*)d_in[7];
    const float* norm1_b     = (const float*)d_in[8];
    const float* temperature = (const float*)d_in[9];
    const float* qkv_w       = (const float*)d_in[10];
    const float* qkv_dw_w    = (const float*)d_in[11];
    const float* proj_w      = (const float*)d_in[12];
    const float* norm2_w     = (const float*)d_in[13];
    const float* norm2_b     = (const float*)d_in[14];
    const float* ffn_in_w    = (const float*)d_in[15];
    const float* ffn_dw_w    = (const float*)d_in[16];
    const float* ffn_out_w   = (const float*)d_in[17];
    float* out = (float*)d_out;
    (void)in_sizes; (void)n_in; (void)out_size; (void)ws_size;

    char* ws = (char*)d_ws;
    bf16* xnext_pm = (bf16*)(ws + OFF_XNEXT);
    bf16* up_pm    = (bf16*)(ws + OFF_UP);
    bf16* xprev_pm = (bf16*)(ws + OFF_XPREV);
    bf16* qkv_a    = (bf16*)(ws + OFF_SL1);
    bf16* h1       = (bf16*)(ws + OFF_SL1);
    bf16* qkv_b    = (bf16*)(ws + OFF_SL2);
    bf16* gbuf     = (bf16*)(ws + OFF_SL2);
    bf16* y1       = (bf16*)(ws + OFF_SL3);
    bf16* atto     = (bf16*)(ws + OFF_SL3);
    bf16* x_pm     = (bf16*)(ws + OFF_SL4);
    bf16* y2       = (bf16*)(ws + OFF_SL5);
    bf16* Wup      = (bf16*)(ws + OFF_WUP);
    bf16* Wqkv     = (bf16*)(ws + OFF_WQKV);
    bf16* Wprj     = (bf16*)(ws + OFF_WPRJ);
    bf16* Wfin     = (bf16*)(ws + OFF_WFIN);
    bf16* Wfout    = (bf16*)(ws + OFF_WFOUT);
    bf16* Wtap     = (bf16*)(ws + OFF_WTAP);
    bf16* zpage    = (bf16*)(ws + OFF_ZP);
    float* nbuf    = (float*)(ws + OFF_NBUF);
    float* Sbuf    = (float*)(ws + OFF_S);

    // zero nbuf + S (adjacent) and the zero page
    hipMemsetAsync(nbuf, 0, 8192 + 131072, stream);
    hipMemsetAsync(zpage, 0, 256, stream);

    // weight conversions
    conv_pad<<<dim3(512), 256, 0, stream>>>(up_w, Wup, 512, 256, 512, 256);
    conv_pad<<<dim3(192), 256, 0, stream>>>(qkv_w, Wqkv, 384, 128, 384, 128);
    conv_pad<<<dim3(64), 256, 0, stream>>>(proj_w, Wprj, 128, 128, 128, 128);
    conv_pad<<<dim3(384), 256, 0, stream>>>(ffn_in_w, Wfin, 680, 128, MFI, 128);
    conv_pad<<<dim3(176), 256, 0, stream>>>(ffn_out_w, Wfout, 128, 340, 128, KFF);
    wtap_prep<<<dim3(288), 256, 0, stream>>>(down_w, Wtap);

    // transposes to pixel-major
    transpose_c2p<<<dim3(128, 8, BATCH), 256, 0, stream>>>(x_next, xnext_pm, 256, 4096);
    transpose_c2p<<<dim3(2048, 2, BATCH), 256, 0, stream>>>(x_prev, xprev_pm, 64, 65536);

    // up 1x1 conv (GEMM): up_pm[b][4096][512]
    gemm_mfma<0><<<dim3(32, 4, BATCH), 256, 0, stream>>>(
        xnext_pm, Wup, 256, 4096, 512, 512, up_pm,
        nullptr, nullptr, nullptr, nullptr, nullptr, nullptr);

    // down-conv MFMA + residual + shuffle + LN1 -> y1
    down_mfma_ln<<<dim3(128, BATCH), 256, 0, stream>>>(
        xprev_pm, x_main, up_pm, Wtap, alpha_down, alpha_up, norm1_w, norm1_b,
        zpage, y1);

    // qkv 1x1 (GEMM): qkv_a[b][16384][384]
    gemm_mfma<0><<<dim3(128, 3, BATCH), 256, 0, stream>>>(
        y1, Wqkv, 128, NPIX, 384, 384, qkv_a,
        nullptr, nullptr, nullptr, nullptr, nullptr, nullptr);

    // depthwise 3x3 -> qkv_b
    dw_qkv<<<dim3(128, 12, BATCH), 256, 0, stream>>>(qkv_a, qkv_dw_w, qkv_b);

    // q/k norms, scores, softmax, attn@v
    rownorm<<<dim3(256), 256, 0, stream>>>(qkv_b, nbuf);
    scores<<<dim3(32, 64), 256, 0, stream>>>(qkv_b, Sbuf);
    softmax_k<<<dim3(32), 32, 0, stream>>>(Sbuf, nbuf, temperature);
    attnapply<<<dim3(32, 16), 256, 0, stream>>>(qkv_b, Sbuf, atto);

    // proj GEMM + residual + fused LN2 -> x_pm (bf16) + y2
    gemm_mfma<1><<<dim3(128, 1, BATCH), 256, 0, stream>>>(
        atto, Wprj, 128, NPIX, 128, 128, y2,
        x_main, x_pm, norm2_w, norm2_b, nullptr, nullptr);

    // ffn_in GEMM -> h1[b][16384][680]
    gemm_mfma<0><<<dim3(128, 6, BATCH), 256, 0, stream>>>(
        y2, Wfin, 128, NPIX, 680, 680, h1,
        nullptr, nullptr, nullptr, nullptr, nullptr, nullptr);

    // dw + gelu gate -> g[b][16384][352]
    dw_gate<<<dim3(128, 11, BATCH), 256, 0, stream>>>(h1, ffn_dw_w, gbuf);

    // ffn_out GEMM + residual -> out (NCHW f32)
    gemm_mfma<2><<<dim3(128, 1, BATCH), 256, 0, stream>>>(
        gbuf, Wfout, KFF, NPIX, 128, 128, nullptr,
        nullptr, nullptr, nullptr, nullptr, x_pm, out);
}

// Round 4
// 615.661 us; speedup vs baseline: 3.7363x; 1.1242x over previous
//
#include <hip/hip_runtime.h>
#include <hip/hip_bf16.h>
#include <math.h>

using bf16 = __hip_bfloat16;
#define DEV static __device__ __forceinline__

typedef float    fx4   __attribute__((ext_vector_type(4)));
typedef float    fx2   __attribute__((ext_vector_type(2)));
typedef short    s16x8 __attribute__((ext_vector_type(8)));
typedef short    s16x4 __attribute__((ext_vector_type(4)));
typedef __bf16   bfx8  __attribute__((ext_vector_type(8)));
typedef unsigned int u32x4 __attribute__((ext_vector_type(4)));

constexpr int BATCH = 8;
constexpr int NPIX  = 16384;      // 128x128
constexpr int KFF   = 352;        // padded K for ffn_out
constexpr int MFI   = 768;        // padded M for ffn_in (true 680)
constexpr int H1S   = 704;        // h1 stride: halves at 0 and 352

DEV float uu2f(unsigned short u) { return __uint_as_float(((unsigned)u) << 16); }
DEV unsigned short f2us(float f) { bf16 h = __float2bfloat16(f); return *(unsigned short*)&h; }
DEV float bl2f(bf16 v) { return __bfloat162float(v); }

// ---------------- workspace layout (bytes) ----------------
constexpr size_t OFF_SL1   = 0;                    // {xnext,up,xprev} -> qkv_a -> h1
constexpr size_t OFF_XNEXT = OFF_SL1;              // 16.78MB
constexpr size_t OFF_UP    = OFF_SL1 + 16777216;   // 33.55MB
constexpr size_t OFF_XPREV = OFF_SL1 + 50331648;   // 67.1MB
constexpr size_t SZ_SL1    = 184549376;            // h1 = 8*16384*704*2
constexpr size_t OFF_SL2   = OFF_SL1 + SZ_SL1;     // qkv_b -> g
constexpr size_t OFF_SL3   = OFF_SL2 + 100663296;  // y1 -> atto
constexpr size_t OFF_SL4   = OFF_SL3 + 33554432;   // x (bf16 pm)
constexpr size_t OFF_SL5   = OFF_SL4 + 33554432;   // y2
constexpr size_t OFF_W     = OFF_SL5 + 33554432;
constexpr size_t OFF_WUP   = OFF_W;                // 512*256*2
constexpr size_t OFF_WQKV  = OFF_W +  262144;      // 384*128*2
constexpr size_t OFF_WPRJ  = OFF_W +  360448;      // 128*128*2
constexpr size_t OFF_WFIN  = OFF_W +  393216;      // 768*128*2
constexpr size_t OFF_WFOUT = OFF_W +  589824;      // 128*352*2
constexpr size_t OFF_WTAP  = OFF_W +  679936;      // 9*128*64*2
constexpr size_t OFF_ZP    = OFF_W +  827392;      // 256B zero page
constexpr size_t OFF_NBUF  = OFF_W +  974848;      // 8*256*4
constexpr size_t OFF_S     = OFF_W +  983040;      // 32*1024*4

// ---------------------------------------------------------------------------
__global__ void conv_pad(const float* __restrict__ src, bf16* __restrict__ dst,
                         int Rs, int Cs, int Rd, int Cd)
{
    int n = Rd * Cd;
    for (int i = blockIdx.x * 256 + threadIdx.x; i < n; i += gridDim.x * 256) {
        int r = i / Cd, c = i % Cd;
        dst[i] = (r < Rs && c < Cs) ? __float2bfloat16(src[r * Cs + c]) : bf16(0.f);
    }
}

// down_w [128co][64ci][9] f32 -> wtap [9][128co][64ci] bf16
__global__ void wtap_prep(const float* __restrict__ src, bf16* __restrict__ dst)
{
    int i = blockIdx.x * 256 + threadIdx.x;
    if (i >= 9 * 128 * 64) return;
    int tap = i >> 13, rm = i & 8191, co = rm >> 6, ci = rm & 63;
    dst[i] = __float2bfloat16(src[(co * 64 + ci) * 9 + tap]);
}

// zero h1 pad columns [340,352) and [692,704)
__global__ void h1_padzero(bf16* __restrict__ h1)
{
    size_t idx = (size_t)blockIdx.x * 256 + threadIdx.x;
    if (idx >= (size_t)BATCH * NPIX * 24) return;
    size_t n = idx / 24;
    int j = (int)(idx % 24);
    int col = (j < 12) ? 340 + j : 680 + j;     // 340..351 or 692..703
    h1[n * H1S + col] = bf16(0.f);
}

// NCHW f32 -> pixel-major bf16 transpose
__global__ __launch_bounds__(256) void transpose_c2p(
    const float* __restrict__ in, bf16* __restrict__ out, int C, int HW)
{
    __shared__ float ts[32][33];
    int hw0 = blockIdx.x * 32, c0 = blockIdx.y * 32, b = blockIdx.z;
    int rl = threadIdx.x >> 5, cl = threadIdx.x & 31;
#pragma unroll
    for (int i = 0; i < 4; i++)
        ts[rl + i * 8][cl] = in[((size_t)b * C + c0 + rl + i * 8) * HW + hw0 + cl];
    __syncthreads();
#pragma unroll
    for (int i = 0; i < 4; i++)
        out[((size_t)b * HW + hw0 + rl + i * 8) * C + c0 + cl] =
            __float2bfloat16(ts[cl][rl + i * 8]);
}

// ---------------------------------------------------------------------------
// MFMA GEMM (single m-tile): D[b][n][co] = sum_k Act[b][n][k] * Wt[co][k]
// EPI 0: store bf16 pm; EPI 1: residual+LN2; EPI 2: residual -> f32 NCHW
// ---------------------------------------------------------------------------
template <int EPI>
__global__ __launch_bounds__(256) void gemm_mfma(
    const bf16* __restrict__ Act, const bf16* __restrict__ Wt,
    int K, int Npb, int Mtrue, int Mstride,
    bf16* __restrict__ outB,
    const float* __restrict__ xmain, bf16* __restrict__ x_out,
    const float* __restrict__ nw, const float* __restrict__ nb,
    const bf16* __restrict__ xres, float* __restrict__ outF)
{
    __shared__ short As[128 * 32];
    __shared__ short Bs[128 * 32];
    const int t = threadIdx.x;
    const int w = t >> 6, lane = t & 63;
    const int wr = w >> 1, wc = w & 1;
    const int lr = lane & 15, lg = lane >> 4;
    const int n0 = blockIdx.x * 128;
    const int m0 = blockIdx.y * 128;
    const int b  = blockIdx.z;
    const bf16* Abase = Act + (size_t)b * Npb * K;

    fx4 acc[4][4];
#pragma unroll
    for (int i = 0; i < 4; i++)
#pragma unroll
        for (int j = 0; j < 4; j++) acc[i][j] = fx4{0.f, 0.f, 0.f, 0.f};

    const int f0 = w * 128 + lane, f1 = f0 + 64;
    const int r0 = f0 >> 2, c0 = (f0 & 3) * 8;
    const int r1 = f1 >> 2, c1 = (f1 & 3) * 8;

    for (int ks = 0; ks < K; ks += 32) {
        __builtin_amdgcn_global_load_lds(
            (const __attribute__((address_space(1))) void*)(Abase + (size_t)(n0 + r0) * K + ks + c0),
            (__attribute__((address_space(3))) void*)(As + w * 1024), 16, 0, 0);
        __builtin_amdgcn_global_load_lds(
            (const __attribute__((address_space(1))) void*)(Abase + (size_t)(n0 + r1) * K + ks + c1),
            (__attribute__((address_space(3))) void*)(As + w * 1024 + 512), 16, 0, 0);
        __builtin_amdgcn_global_load_lds(
            (const __attribute__((address_space(1))) void*)(Wt + (size_t)(m0 + r0) * K + ks + c0),
            (__attribute__((address_space(3))) void*)(Bs + w * 1024), 16, 0, 0);
        __builtin_amdgcn_global_load_lds(
            (const __attribute__((address_space(1))) void*)(Wt + (size_t)(m0 + r1) * K + ks + c1),
            (__attribute__((address_space(3))) void*)(Bs + w * 1024 + 512), 16, 0, 0);
        __syncthreads();
        bfx8 af[4], bw[4];
#pragma unroll
        for (int mi = 0; mi < 4; mi++)
            af[mi] = __builtin_bit_cast(bfx8,
                *(const s16x8*)&As[(wr * 64 + mi * 16 + lr) * 32 + lg * 8]);
#pragma unroll
        for (int ni = 0; ni < 4; ni++)
            bw[ni] = __builtin_bit_cast(bfx8,
                *(const s16x8*)&Bs[(wc * 64 + ni * 16 + lr) * 32 + lg * 8]);
#pragma unroll
        for (int mi = 0; mi < 4; mi++)
#pragma unroll
            for (int ni = 0; ni < 4; ni++)
                acc[mi][ni] = __builtin_amdgcn_mfma_f32_16x16x32_bf16(
                    af[mi], bw[ni], acc[mi][ni], 0, 0, 0);
        __syncthreads();
    }

    if (EPI == 0) {
#pragma unroll
        for (int mi = 0; mi < 4; mi++)
#pragma unroll
            for (int ni = 0; ni < 4; ni++) {
                int co = m0 + wc * 64 + ni * 16 + lr;
                if (co < Mtrue) {
#pragma unroll
                    for (int r = 0; r < 4; r++) {
                        int px = n0 + wr * 64 + mi * 16 + lg * 4 + r;
                        outB[((size_t)b * Npb + px) * Mstride + co] =
                            __float2bfloat16(acc[mi][ni][r]);
                    }
                }
            }
    } else if (EPI == 1) {
        float xv[4][4][4];
#pragma unroll
        for (int mi = 0; mi < 4; mi++)
#pragma unroll
            for (int ni = 0; ni < 4; ni++) {
                int co = wc * 64 + ni * 16 + lr;
                fx4 x4 = *(const fx4*)&xmain[((size_t)b * 128 + co) * 16384 +
                                             n0 + wr * 64 + mi * 16 + lg * 4];
#pragma unroll
                for (int r = 0; r < 4; r++) xv[mi][ni][r] = x4[r] + acc[mi][ni][r];
            }
        __shared__ float ps[2][128];
        __shared__ float pss[2][128];
#pragma unroll
        for (int mi = 0; mi < 4; mi++)
#pragma unroll
            for (int r = 0; r < 4; r++) {
                float s = 0.f, s2 = 0.f;
#pragma unroll
                for (int ni = 0; ni < 4; ni++) {
                    float v = xv[mi][ni][r]; s += v; s2 += v * v;
                }
#pragma unroll
                for (int m = 1; m < 16; m <<= 1) {
                    s  += __shfl_xor(s, m);
                    s2 += __shfl_xor(s2, m);
                }
                if (lr == 0) {
                    int row = wr * 64 + mi * 16 + lg * 4 + r;
                    ps[wc][row] = s; pss[wc][row] = s2;
                }
            }
        __syncthreads();
        float nwv[4], nbv[4];
#pragma unroll
        for (int ni = 0; ni < 4; ni++) {
            int co = wc * 64 + ni * 16 + lr;
            nwv[ni] = nw[co]; nbv[ni] = nb[co];
        }
#pragma unroll
        for (int mi = 0; mi < 4; mi++)
#pragma unroll
            for (int r = 0; r < 4; r++) {
                int row = wr * 64 + mi * 16 + lg * 4 + r;
                float s  = ps[0][row] + ps[1][row];
                float s2 = pss[0][row] + pss[1][row];
                float mu = s * (1.f / 128.f);
                float var = s2 * (1.f / 128.f) - mu * mu;
                float rstd = rsqrtf(var + 1e-5f);
                size_t px = (size_t)b * 16384 + n0 + row;
#pragma unroll
                for (int ni = 0; ni < 4; ni++) {
                    int co = wc * 64 + ni * 16 + lr;
                    float v = xv[mi][ni][r];
                    x_out[px * 128 + co] = __float2bfloat16(v);
                    outB[px * 128 + co] = __float2bfloat16((v - mu) * rstd * nwv[ni] + nbv[ni]);
                }
            }
    } else {  // EPI 2
#pragma unroll
        for (int mi = 0; mi < 4; mi++)
#pragma unroll
            for (int ni = 0; ni < 4; ni++) {
                int co = wc * 64 + ni * 16 + lr;
                int pxb = n0 + wr * 64 + mi * 16 + lg * 4;
                fx4 o;
#pragma unroll
                for (int r = 0; r < 4; r++)
                    o[r] = acc[mi][ni][r] +
                           bl2f(xres[((size_t)b * 16384 + pxb + r) * 128 + co]);
                *(fx4*)&outF[((size_t)b * 128 + co) * 16384 + pxb] = o;
            }
    }
}

// ---------------------------------------------------------------------------
// MFMA GEMM with m-tile loop (K=128 fixed): stages full A once, loops B tiles.
// REMAP=1: h1 column remap (co>=340 -> co+12), stride 704.
// ---------------------------------------------------------------------------
template <int REMAP>
__global__ __launch_bounds__(256) void gemm_mloop(
    const bf16* __restrict__ Act, const bf16* __restrict__ Wt,
    int nM, int Mtrue, int Mstride, bf16* __restrict__ outB)
{
    __shared__ short As[16384];   // [4 kb][128 row][32]
    __shared__ short Bs[16384];
    const int t = threadIdx.x;
    const int w = t >> 6, lane = t & 63;
    const int wr = w >> 1, wc = w & 1;
    const int lr = lane & 15, lg = lane >> 4;
    const int n0 = blockIdx.x * 128;
    const int b  = blockIdx.y;
    const short* Abase = (const short*)Act + (size_t)b * NPIX * 128;

    // stage A once: 2048 chunks of 16B
#pragma unroll
    for (int i = 0; i < 8; i++) {
        int chunk = i * 256 + w * 64 + lane;
        int kb = chunk >> 9, row = (chunk >> 2) & 127, c8 = chunk & 3;
        __builtin_amdgcn_global_load_lds(
            (const __attribute__((address_space(1))) void*)
                (Abase + (size_t)(n0 + row) * 128 + kb * 32 + c8 * 8),
            (__attribute__((address_space(3))) void*)(As + i * 2048 + w * 512), 16, 0, 0);
    }

    for (int mt = 0; mt < nM; mt++) {
#pragma unroll
        for (int i = 0; i < 8; i++) {
            int chunk = i * 256 + w * 64 + lane;
            int kb = chunk >> 9, row = (chunk >> 2) & 127, c8 = chunk & 3;
            __builtin_amdgcn_global_load_lds(
                (const __attribute__((address_space(1))) void*)
                    ((const short*)Wt + (size_t)(mt * 128 + row) * 128 + kb * 32 + c8 * 8),
                (__attribute__((address_space(3))) void*)(Bs + i * 2048 + w * 512), 16, 0, 0);
        }
        __syncthreads();
        fx4 acc[4][4];
#pragma unroll
        for (int i = 0; i < 4; i++)
#pragma unroll
            for (int j = 0; j < 4; j++) acc[i][j] = fx4{0.f, 0.f, 0.f, 0.f};
#pragma unroll
        for (int ks = 0; ks < 4; ks++) {
            bfx8 af[4], bw[4];
#pragma unroll
            for (int mi = 0; mi < 4; mi++)
                af[mi] = __builtin_bit_cast(bfx8,
                    *(const s16x8*)&As[ks * 4096 + (wr * 64 + mi * 16 + lr) * 32 + lg * 8]);
#pragma unroll
            for (int ni = 0; ni < 4; ni++)
                bw[ni] = __builtin_bit_cast(bfx8,
                    *(const s16x8*)&Bs[ks * 4096 + (wc * 64 + ni * 16 + lr) * 32 + lg * 8]);
#pragma unroll
            for (int mi = 0; mi < 4; mi++)
#pragma unroll
                for (int ni = 0; ni < 4; ni++)
                    acc[mi][ni] = __builtin_amdgcn_mfma_f32_16x16x32_bf16(
                        af[mi], bw[ni], acc[mi][ni], 0, 0, 0);
        }
        __syncthreads();
#pragma unroll
        for (int mi = 0; mi < 4; mi++)
#pragma unroll
            for (int ni = 0; ni < 4; ni++) {
                int co = mt * 128 + wc * 64 + ni * 16 + lr;
                if (co < Mtrue) {
                    int cd = (REMAP && co >= 340) ? co + 12 : co;
#pragma unroll
                    for (int r = 0; r < 4; r++) {
                        int px = n0 + wr * 64 + mi * 16 + lg * 4 + r;
                        outB[((size_t)b * NPIX + px) * Mstride + cd] =
                            __float2bfloat16(acc[mi][ni][r]);
                    }
                }
            }
    }
}

// ---------------------------------------------------------------------------
// down-conv(3x3,s2) as 9-tap MFMA GEMM + residual + pixel-shuffle + LN1 -> y1
// ---------------------------------------------------------------------------
__global__ __launch_bounds__(256) void down_mfma_ln(
    const bf16* __restrict__ xprev_pm,   // [b][65536][64]
    const float* __restrict__ xmain,     // NCHW f32
    const bf16* __restrict__ up_pm,      // [b][4096][512]
    const bf16* __restrict__ wtap,       // [9][128co][64ci]
    const float* __restrict__ alpha_d, const float* __restrict__ alpha_u,
    const float* __restrict__ n1w, const float* __restrict__ n1b,
    const bf16* __restrict__ zeropage,
    bf16* __restrict__ y1)               // [b][16384][128]
{
    __shared__ short As[128 * 64];
    __shared__ short Bs[128 * 64];
    __shared__ float ps[2][128];
    __shared__ float pss[2][128];
    const int t = threadIdx.x;
    const int w = t >> 6, lane = t & 63;
    const int wr = w >> 1, wc = w & 1;
    const int lr = lane & 15, lg = lane >> 4;
    const int y = blockIdx.x;
    const int b = blockIdx.y;

    const int srow0 = 32 * w + (lane >> 3);
    const int sci8  = lane & 7;
    const short* wtbase = (const short*)wtap;

    fx4 acc[4][4];
#pragma unroll
    for (int i = 0; i < 4; i++)
#pragma unroll
        for (int j = 0; j < 4; j++) acc[i][j] = fx4{0.f, 0.f, 0.f, 0.f};

#pragma unroll
    for (int tap = 0; tap < 9; tap++) {
        const int dy = tap / 3, dx = tap % 3;
        const int iy = 2 * y - 1 + dy;
        const bool rowok = (iy >= 0) && (iy < 256);
        const short* arow = (const short*)xprev_pm +
                            (((size_t)b * 65536 + (size_t)iy * 256) * 64);
#pragma unroll
        for (int i = 0; i < 4; i++) {
            int row = srow0 + 8 * i;
            int ix = 2 * row - 1 + dx;
            const short* src = (rowok && ix >= 0 && ix < 256)
                                 ? (arow + (size_t)ix * 64 + sci8 * 8)
                                 : (const short*)zeropage;
            __builtin_amdgcn_global_load_lds(
                (const __attribute__((address_space(1))) void*)src,
                (__attribute__((address_space(3))) void*)(As + w * 2048 + i * 512), 16, 0, 0);
            __builtin_amdgcn_global_load_lds(
                (const __attribute__((address_space(1))) void*)
                    (wtbase + tap * 8192 + w * 2048 + i * 512 + lane * 8),
                (__attribute__((address_space(3))) void*)(Bs + w * 2048 + i * 512), 16, 0, 0);
        }
        __syncthreads();
        bfx8 af[4][2], bw[4][2];
#pragma unroll
        for (int mi = 0; mi < 4; mi++)
#pragma unroll
            for (int ks = 0; ks < 2; ks++)
                af[mi][ks] = __builtin_bit_cast(bfx8,
                    *(const s16x8*)&As[(wr * 64 + mi * 16 + lr) * 64 + ks * 32 + lg * 8]);
#pragma unroll
        for (int ni = 0; ni < 4; ni++)
#pragma unroll
            for (int ks = 0; ks < 2; ks++)
                bw[ni][ks] = __builtin_bit_cast(bfx8,
                    *(const s16x8*)&Bs[(wc * 64 + ni * 16 + lr) * 64 + ks * 32 + lg * 8]);
#pragma unroll
        for (int mi = 0; mi < 4; mi++)
#pragma unroll
            for (int ni = 0; ni < 4; ni++)
#pragma unroll
                for (int ks = 0; ks < 2; ks++)
                    acc[mi][ni] = __builtin_amdgcn_mfma_f32_16x16x32_bf16(
                        af[mi][ks], bw[ni][ks], acc[mi][ni], 0, 0, 0);
        __syncthreads();
    }

    const float ad = alpha_d[0], au = alpha_u[0];
    const int n2base = (y >> 1) * 64;
    const int chb2 = (y & 1) * 2;
    float fv[4][4][4];
#pragma unroll
    for (int mi = 0; mi < 4; mi++) {
        const int x0 = wr * 64 + mi * 16 + lg * 4;
#pragma unroll
        for (int ni = 0; ni < 4; ni++) {
            const int co = wc * 64 + ni * 16 + lr;
            fx4 xm = *(const fx4*)&xmain[(((size_t)b * 128 + co) * 128 + y) * 128 + x0];
            const short* uprow = (const short*)up_pm +
                ((size_t)b * 4096 + n2base + (x0 >> 1)) * 512 + co * 4 + chb2;
            unsigned up01 = *(const unsigned*)uprow;
            unsigned up23 = *(const unsigned*)(uprow + 512);
            fv[mi][ni][0] = xm[0] + ad * acc[mi][ni][0] + au * uu2f((unsigned short)(up01 & 0xffff));
            fv[mi][ni][1] = xm[1] + ad * acc[mi][ni][1] + au * uu2f((unsigned short)(up01 >> 16));
            fv[mi][ni][2] = xm[2] + ad * acc[mi][ni][2] + au * uu2f((unsigned short)(up23 & 0xffff));
            fv[mi][ni][3] = xm[3] + ad * acc[mi][ni][3] + au * uu2f((unsigned short)(up23 >> 16));
        }
    }
#pragma unroll
    for (int mi = 0; mi < 4; mi++)
#pragma unroll
        for (int r = 0; r < 4; r++) {
            float s = 0.f, s2 = 0.f;
#pragma unroll
            for (int ni = 0; ni < 4; ni++) {
                float v = fv[mi][ni][r]; s += v; s2 += v * v;
            }
#pragma unroll
            for (int m = 1; m < 16; m <<= 1) {
                s  += __shfl_xor(s, m);
                s2 += __shfl_xor(s2, m);
            }
            if (lr == 0) {
                int row = wr * 64 + mi * 16 + lg * 4 + r;
                ps[wc][row] = s; pss[wc][row] = s2;
            }
        }
    __syncthreads();
    float nwv[4], nbv[4];
#pragma unroll
    for (int ni = 0; ni < 4; ni++) {
        int co = wc * 64 + ni * 16 + lr;
        nwv[ni] = n1w[co]; nbv[ni] = n1b[co];
    }
#pragma unroll
    for (int mi = 0; mi < 4; mi++)
#pragma unroll
        for (int r = 0; r < 4; r++) {
            int row = wr * 64 + mi * 16 + lg * 4 + r;
            float s  = ps[0][row] + ps[1][row];
            float s2 = pss[0][row] + pss[1][row];
            float mu = s * (1.f / 128.f);
            float var = s2 * (1.f / 128.f) - mu * mu;
            float rstd = rsqrtf(var + 1e-5f);
            size_t px = (size_t)b * 16384 + (size_t)y * 128 + row;
#pragma unroll
            for (int ni = 0; ni < 4; ni++) {
                int co = wc * 64 + ni * 16 + lr;
                ((short*)y1)[px * 128 + co] =
                    (short)f2us((fv[mi][ni][r] - mu) * rstd * nwv[ni] + nbv[ni]);
            }
        }
}

// ---------------------------------------------------------------------------
// depthwise 3x3 accumulator: 6 LDS rows -> 4 output rows, 8 ch (4 fx2) per thread
// L: [10 rows][34 pos][40 ch-shorts], swb: [9 taps][32 ch] f32 in LDS
// ---------------------------------------------------------------------------
DEV void dw_accum(const short* __restrict__ L, const float* __restrict__ swb,
                  int x, int yh, int lofs, fx2 acc[4][4])
{
    fx2 wreg[9][4];
#pragma unroll
    for (int tap = 0; tap < 9; tap++)
#pragma unroll
        for (int k = 0; k < 4; k++)
            wreg[tap][k] = *(const fx2*)&swb[tap * 32 + lofs + 2 * k];
#pragma unroll
    for (int yy = 0; yy < 4; yy++)
#pragma unroll
        for (int k = 0; k < 4; k++) acc[yy][k] = fx2{0.f, 0.f};
#pragma unroll
    for (int r = 0; r < 6; r++) {
        fx2 rv[3][4];
#pragma unroll
        for (int dxp = 0; dxp < 3; dxp++) {
            s16x8 raw = *(const s16x8*)&L[((yh * 4 + r) * 34 + x + dxp) * 40 + lofs];
            u32x4 u = __builtin_bit_cast(u32x4, raw);
#pragma unroll
            for (int k = 0; k < 4; k++)
                rv[dxp][k] = fx2{__uint_as_float(u[k] << 16),
                                 __uint_as_float(u[k] & 0xffff0000u)};
        }
#pragma unroll
        for (int yy = 0; yy < 4; yy++) {
            int dy = r - yy;
            if (dy < 0 || dy > 2) continue;
#pragma unroll
            for (int dx = 0; dx < 3; dx++)
#pragma unroll
                for (int k = 0; k < 4; k++)
                    acc[yy][k] += rv[dx][k] * wreg[dy * 3 + dx][k];
        }
    }
}

// ---------------------------------------------------------------------------
// depthwise 3x3 pad=1, pixel-major. GATE=1: gelu(dw(h1a)) * dw(h1b) from
// stride-704 h1; GATE=0: plain (qkv, stride 384) + fused q/k sumsq (QKNORM).
// Tile 32x x 8y x 32ch; thread = (x, chg, yh) owns 1x * 4y * 8ch.
// ---------------------------------------------------------------------------
template <int GATE, int QKNORM>
__global__ __launch_bounds__(256) void dw_conv(
    const bf16* __restrict__ in, const float* __restrict__ w,
    bf16* __restrict__ out, float* __restrict__ nbuf)
{
    constexpr int CHST  = GATE ? 704 : 384;
    constexpr int CHOST = GATE ? 352 : 384;
    __shared__ short L1[13600];                 // [10][34][40]
    __shared__ short L2[GATE ? 13600 : 8];
    __shared__ float sw1[288];                  // [9][32]
    __shared__ float sw2[GATE ? 288 : 8];
    __shared__ float snorm[32];
    const int t = threadIdx.x;
    const int x = t & 31, chg = (t >> 5) & 3, yh = t >> 7;
    const int cg = blockIdx.y, b = blockIdx.z;
    const int x0 = (blockIdx.x & 3) * 32, y0 = (blockIdx.x >> 2) * 8;

    if (QKNORM && t < 32) snorm[t] = 0.f;
    // stage weights [9][32]
    if (GATE) {
        for (int i = t; i < 288; i += 256) {
            int c = i & 31, tap = i >> 5;
            int cr = cg * 32 + c;
            sw1[i] = (cr < 340) ? w[cr * 9 + tap] : 0.f;
            sw2[i] = (cr < 340) ? w[(cr + 340) * 9 + tap] : 0.f;
        }
    } else {
        for (int i = t; i < 288; i += 256) {
            int c = i & 31, tap = i >> 5;
            sw1[i] = w[(cg * 32 + c) * 9 + tap];
        }
    }
    // stage input tile(s)
    const short* bin = (const short*)in + (size_t)b * NPIX * CHST + cg * 32;
    const int NCHK = GATE ? 2720 : 1360;
    for (int id = t; id < NCHK; id += 256) {
        int half = 0, idd = id;
        if (GATE && idd >= 1360) { half = 1; idd -= 1360; }
        int row = idd / 136, rm = idd % 136, pos = rm >> 2, c8 = rm & 3;
        int gy = y0 - 1 + row, gx = x0 - 1 + pos;
        s16x8 v = s16x8{0, 0, 0, 0, 0, 0, 0, 0};
        if (gy >= 0 && gy < 128 && gx >= 0 && gx < 128)
            v = *(const s16x8*)(bin + ((size_t)(gy << 7) + gx) * CHST + half * 352 + c8 * 8);
        short* dst = (GATE && half) ? L2 : L1;
        *(s16x8*)&dst[(row * 34 + pos) * 40 + c8 * 8] = v;
    }
    __syncthreads();

    const int lofs = chg * 8;
    fx2 a1[4][4];
    dw_accum(L1, sw1, x, yh, lofs, a1);
    if (GATE) {
        // gelu (tanh form, exp2-based): g = x / (1 + 2^{-z'}), z' = x*(c1*x^2 + c0)*log2e*2
#pragma unroll
        for (int yy = 0; yy < 4; yy++)
#pragma unroll
            for (int k = 0; k < 4; k++) {
                fx2 v = a1[yy][k];
#pragma unroll
                for (int e = 0; e < 2; e++) {
                    float xx = v[e];
                    float x2 = xx * xx;
                    float mzz = xx * fmaf(-0.1029432f, x2, -2.3022082f);
                    float un = exp2f(mzz);
                    v[e] = xx * __builtin_amdgcn_rcpf(1.f + un);
                }
                a1[yy][k] = v;
            }
        fx2 a2[4][4];
        dw_accum(L2, sw2, x, yh, lofs, a2);
#pragma unroll
        for (int yy = 0; yy < 4; yy++)
#pragma unroll
            for (int k = 0; k < 4; k++) a1[yy][k] *= a2[yy][k];
    }

    if (QKNORM && cg < 8) {
        fx2 sq[4];
#pragma unroll
        for (int k = 0; k < 4; k++) {
            sq[k] = fx2{0.f, 0.f};
#pragma unroll
            for (int yy = 0; yy < 4; yy++) sq[k] += a1[yy][k] * a1[yy][k];
        }
#pragma unroll
        for (int m = 1; m < 32; m <<= 1)
#pragma unroll
            for (int k = 0; k < 4; k++) {
                sq[k][0] += __shfl_xor(sq[k][0], m);
                sq[k][1] += __shfl_xor(sq[k][1], m);
            }
        if (x == 0) {
#pragma unroll
            for (int k = 0; k < 4; k++) {
                atomicAdd(&snorm[chg * 8 + 2 * k],     sq[k][0]);
                atomicAdd(&snorm[chg * 8 + 2 * k + 1], sq[k][1]);
            }
        }
    }

#pragma unroll
    for (int yy = 0; yy < 4; yy++) {
        s16x8 pk;
#pragma unroll
        for (int k = 0; k < 4; k++) {
            pk[2 * k]     = (short)f2us(a1[yy][k][0]);
            pk[2 * k + 1] = (short)f2us(a1[yy][k][1]);
        }
        *(s16x8*)((short*)out + (((size_t)b * NPIX) + ((y0 + yh * 4 + yy) << 7) + x0 + x) * CHOST
                  + cg * 32 + chg * 8) = pk;
    }

    if (QKNORM) {
        __syncthreads();
        if (cg < 8 && t < 32)
            atomicAdd(&nbuf[b * 256 + cg * 32 + t], snorm[t]);
    }
}

// ---------------------------------------------------------------------------
// raw scores S[bh][i][j] += sum_{n chunk} q[n][i]*k[n][j]   (S pre-zeroed)
// ---------------------------------------------------------------------------
__global__ __launch_bounds__(256) void scores(const bf16* __restrict__ qkv,
                                              float* __restrict__ S)
{
    __shared__ short qs[256 * 40];
    __shared__ short ks2[256 * 40];
    const int t = threadIdx.x;
    const int bh = blockIdx.x, b = bh >> 2, h = bh & 3;
    const int n0 = blockIdx.y * 256;
    {
        const short* src = (const short*)qkv + ((size_t)(b * 16384 + n0 + t)) * 384 + h * 32;
#pragma unroll
        for (int i = 0; i < 4; i++) {
            *(s16x8*)&qs[t * 40 + i * 8]  = *(const s16x8*)(src + i * 8);
            *(s16x8*)&ks2[t * 40 + i * 8] = *(const s16x8*)(src + 128 + i * 8);
        }
    }
    __syncthreads();
    const int i2 = t >> 4, j16 = t & 15;
    float a00 = 0.f, a01 = 0.f, a10 = 0.f, a11 = 0.f;
    for (int n = 0; n < 256; n++) {
        unsigned qq = *(const unsigned*)&qs[n * 40 + i2 * 2];
        unsigned kk = *(const unsigned*)&ks2[n * 40 + j16 * 2];
        float q0 = uu2f((unsigned short)(qq & 0xffff)), q1 = uu2f((unsigned short)(qq >> 16));
        float k0 = uu2f((unsigned short)(kk & 0xffff)), k1 = uu2f((unsigned short)(kk >> 16));
        a00 = fmaf(q0, k0, a00); a01 = fmaf(q0, k1, a01);
        a10 = fmaf(q1, k0, a10); a11 = fmaf(q1, k1, a11);
    }
    float* base = S + (size_t)bh * 1024;
    atomicAdd(&base[(i2 * 2 + 0) * 32 + j16 * 2 + 0], a00);
    atomicAdd(&base[(i2 * 2 + 0) * 32 + j16 * 2 + 1], a01);
    atomicAdd(&base[(i2 * 2 + 1) * 32 + j16 * 2 + 0], a10);
    atomicAdd(&base[(i2 * 2 + 1) * 32 + j16 * 2 + 1], a11);
}

// softmax with temperature and q/k norms; in-place on S
__global__ void softmax_k(float* __restrict__ S, const float* __restrict__ nbuf,
                          const float* __restrict__ temp)
{
    __shared__ float invk[32];
    int bh = blockIdx.x, b = bh >> 2, h = bh & 3, i = threadIdx.x;
    invk[i] = 1.f / fmaxf(sqrtf(nbuf[b * 256 + 128 + h * 32 + i]), 1e-12f);
    __syncthreads();
    float ti = temp[h] / fmaxf(sqrtf(nbuf[b * 256 + h * 32 + i]), 1e-12f);
    float* row = S + (size_t)bh * 1024 + i * 32;
    float vals[32], m = -1e30f;
#pragma unroll
    for (int j = 0; j < 32; j++) { vals[j] = row[j] * ti * invk[j]; m = fmaxf(m, vals[j]); }
    float s = 0.f;
#pragma unroll
    for (int j = 0; j < 32; j++) { vals[j] = expf(vals[j] - m); s += vals[j]; }
    float r = 1.f / s;
#pragma unroll
    for (int j = 0; j < 32; j++) row[j] = vals[j] * r;
}

// atto[n][h*32+c] = sum_d attn[c][d] * v[n][d]
__global__ __launch_bounds__(256) void attnapply(const bf16* __restrict__ qkv,
                                                 const float* __restrict__ S,
                                                 bf16* __restrict__ atto)
{
    __shared__ float sa[1024];
    const int t = threadIdx.x;
    const int bh = blockIdx.x, b = bh >> 2, h = bh & 3;
    const int n0 = blockIdx.y * 1024;
    for (int i = t; i < 1024; i += 256) sa[i] = S[(size_t)bh * 1024 + i];
    __syncthreads();
#pragma unroll
    for (int pp = 0; pp < 4; pp++) {
        int n = n0 + (t << 2) + pp;
        const short* vs = (const short*)qkv + ((size_t)(b * 16384) + n) * 384 + 256 + h * 32;
        float v[32];
#pragma unroll
        for (int i = 0; i < 4; i++) {
            s16x8 vv = *(const s16x8*)(vs + i * 8);
#pragma unroll
            for (int e = 0; e < 8; e++) v[i * 8 + e] = uu2f((unsigned short)vv[e]);
        }
        short ov[32];
#pragma unroll
        for (int c = 0; c < 32; c++) {
            const fx4* row = (const fx4*)&sa[c * 32];
            float a = 0.f;
#pragma unroll
            for (int d4 = 0; d4 < 8; d4++) {
                fx4 w4 = row[d4];
                a += w4[0] * v[d4 * 4] + w4[1] * v[d4 * 4 + 1] +
                     w4[2] * v[d4 * 4 + 2] + w4[3] * v[d4 * 4 + 3];
            }
            ov[c] = (short)f2us(a);
        }
        short* dst = (short*)atto + ((size_t)(b * 16384) + n) * 128 + h * 32;
#pragma unroll
        for (int i = 0; i < 4; i++) *(s16x8*)(dst + i * 8) = *(s16x8*)&ov[i * 8];
    }
}

// ---------------------------------------------------------------------------
extern "C" void kernel_launch(void* const* d_in, const int* in_sizes, int n_in,
                              void* d_out, int out_size, void* d_ws, size_t ws_size,
                              hipStream_t stream)
{
    const float* x_main      = (const float*)d_in[0];
    const float* x_prev      = (const float*)d_in[1];
    const float* x_next      = (const float*)d_in[2];
    const float* alpha_down  = (const float*)d_in[3];
    const float* alpha_up    = (const float*)d_in[4];
    const float* down_w      = (const float*)d_in[5];
    const float* up_w        = (const float*)d_in[6];
    const float* norm1_w     = (const float*)d_in[7];
    const float* norm1_b     = (const float*)d_in[8];
    const float* temperature = (const float*)d_in[9];
    const float* qkv_w       = (const float*)d_in[10];
    const float* qkv_dw_w    = (const float*)d_in[11];
    const float* proj_w      = (const float*)d_in[12];
    const float* norm2_w     = (const float*)d_in[13];
    const float* norm2_b     = (const float*)d_in[14];
    const float* ffn_in_w    = (const float*)d_in[15];
    const float* ffn_dw_w    = (const float*)d_in[16];
    const float* ffn_out_w   = (const float*)d_in[17];
    float* out = (float*)d_out;
    (void)in_sizes; (void)n_in; (void)out_size; (void)ws_size;

    char* ws = (char*)d_ws;
    bf16* xnext_pm = (bf16*)(ws + OFF_XNEXT);
    bf16* up_pm    = (bf16*)(ws + OFF_UP);
    bf16* xprev_pm = (bf16*)(ws + OFF_XPREV);
    bf16* qkv_a    = (bf16*)(ws + OFF_SL1);
    bf16* h1       = (bf16*)(ws + OFF_SL1);
    bf16* qkv_b    = (bf16*)(ws + OFF_SL2);
    bf16* gbuf     = (bf16*)(ws + OFF_SL2);
    bf16* y1       = (bf16*)(ws + OFF_SL3);
    bf16* atto     = (bf16*)(ws + OFF_SL3);
    bf16* x_pm     = (bf16*)(ws + OFF_SL4);
    bf16* y2       = (bf16*)(ws + OFF_SL5);
    bf16* Wup      = (bf16*)(ws + OFF_WUP);
    bf16* Wqkv     = (bf16*)(ws + OFF_WQKV);
    bf16* Wprj     = (bf16*)(ws + OFF_WPRJ);
    bf16* Wfin     = (bf16*)(ws + OFF_WFIN);
    bf16* Wfout    = (bf16*)(ws + OFF_WFOUT);
    bf16* Wtap     = (bf16*)(ws + OFF_WTAP);
    bf16* zpage    = (bf16*)(ws + OFF_ZP);
    float* nbuf    = (float*)(ws + OFF_NBUF);
    float* Sbuf    = (float*)(ws + OFF_S);

    hipMemsetAsync(nbuf, 0, 8192 + 131072, stream);
    hipMemsetAsync(zpage, 0, 256, stream);

    conv_pad<<<dim3(512), 256, 0, stream>>>(up_w, Wup, 512, 256, 512, 256);
    conv_pad<<<dim3(192), 256, 0, stream>>>(qkv_w, Wqkv, 384, 128, 384, 128);
    conv_pad<<<dim3(64), 256, 0, stream>>>(proj_w, Wprj, 128, 128, 128, 128);
    conv_pad<<<dim3(384), 256, 0, stream>>>(ffn_in_w, Wfin, 680, 128, MFI, 128);
    conv_pad<<<dim3(176), 256, 0, stream>>>(ffn_out_w, Wfout, 128, 340, 128, KFF);
    wtap_prep<<<dim3(288), 256, 0, stream>>>(down_w, Wtap);

    transpose_c2p<<<dim3(128, 8, BATCH), 256, 0, stream>>>(x_next, xnext_pm, 256, 4096);
    transpose_c2p<<<dim3(2048, 2, BATCH), 256, 0, stream>>>(x_prev, xprev_pm, 64, 65536);

    // up 1x1 conv (GEMM): up_pm[b][4096][512]
    gemm_mfma<0><<<dim3(32, 4, BATCH), 256, 0, stream>>>(
        xnext_pm, Wup, 256, 4096, 512, 512, up_pm,
        nullptr, nullptr, nullptr, nullptr, nullptr, nullptr);

    // down-conv MFMA + residual + shuffle + LN1 -> y1
    down_mfma_ln<<<dim3(128, BATCH), 256, 0, stream>>>(
        xprev_pm, x_main, up_pm, Wtap, alpha_down, alpha_up, norm1_w, norm1_b,
        zpage, y1);

    // qkv 1x1 (GEMM, m-loop): qkv_a[b][16384][384]
    gemm_mloop<0><<<dim3(128, BATCH), 256, 0, stream>>>(y1, Wqkv, 3, 384, 384, qkv_a);

    // depthwise 3x3 -> qkv_b, fused q/k sumsq -> nbuf
    dw_conv<0, 1><<<dim3(64, 12, BATCH), 256, 0, stream>>>(qkv_a, qkv_dw_w, qkv_b, nbuf);

    // scores, softmax, attn@v
    scores<<<dim3(32, 64), 256, 0, stream>>>(qkv_b, Sbuf);
    softmax_k<<<dim3(32), 32, 0, stream>>>(Sbuf, nbuf, temperature);
    attnapply<<<dim3(32, 16), 256, 0, stream>>>(qkv_b, Sbuf, atto);

    // proj GEMM + residual + fused LN2 -> x_pm (bf16) + y2
    gemm_mfma<1><<<dim3(128, 1, BATCH), 256, 0, stream>>>(
        atto, Wprj, 128, NPIX, 128, 128, y2,
        x_main, x_pm, norm2_w, norm2_b, nullptr, nullptr);

    // zero h1 pad columns, then ffn_in GEMM -> h1[b][16384][704]
    h1_padzero<<<dim3((BATCH * NPIX * 24 + 255) / 256), 256, 0, stream>>>(h1);
    gemm_mloop<1><<<dim3(128, BATCH), 256, 0, stream>>>(y2, Wfin, 6, 680, H1S, h1);

    // dw + gelu gate -> g[b][16384][352]
    dw_conv<1, 0><<<dim3(64, 11, BATCH), 256, 0, stream>>>(h1, ffn_dw_w, gbuf, nullptr);

    // ffn_out GEMM + residual -> out (NCHW f32)
    gemm_mfma<2><<<dim3(128, 1, BATCH), 256, 0, stream>>>(
        gbuf, Wfout, KFF, NPIX, 128, 128, nullptr,
        nullptr, nullptr, nullptr, nullptr, x_pm, out);
}